// Round 3
// baseline (165088.208 us; speedup 1.0000x reference)
//
#include <hip/hip_runtime.h>
#include <hip/hip_bf16.h>

// Problem constants
constexpr int kN = 8192;
constexpr int kF = 256;
constexpr int kH = 512;
constexpr int kL = 512;
constexpr int kE = kN * 4;           // 32768 edges

using ull = unsigned long long;

__device__ __forceinline__ float sigm(float x) { return 1.f / (1.f + __expf(-x)); }

__device__ __forceinline__ float4 ld_bf4(const __hip_bfloat16* p) {
    uint2 u = *(const uint2*)p;
    float4 r;
    r.x = __uint_as_float(u.x << 16);
    r.y = __uint_as_float(u.x & 0xffff0000u);
    r.z = __uint_as_float(u.y << 16);
    r.w = __uint_as_float(u.y & 0xffff0000u);
    return r;
}

// stamped 8-byte pair: low = float bits, high = stamp (step+1)
__device__ __forceinline__ void st_pair(ull* p, float v, unsigned stamp) {
    ull u = ((ull)stamp << 32) | (ull)__float_as_uint(v);
    __hip_atomic_store(p, u, __ATOMIC_RELAXED, __HIP_MEMORY_SCOPE_AGENT);
}
__device__ __forceinline__ ull ld_raw(const ull* p) {
    return __hip_atomic_load(p, __ATOMIC_RELAXED, __HIP_MEMORY_SCOPE_AGENT);
}

// ---------------------------------------------------------------------------
__global__ void k_init(float* __restrict__ out, const float* __restrict__ bdo,
                       ull* __restrict__ hpay, ull* __restrict__ zpay,
                       int* __restrict__ claims, int* __restrict__ prog,
                       ull* __restrict__ ring, long ringN) {
    int idx = blockIdx.x * 256 + threadIdx.x;
    if (idx < kE) out[idx] = bdo[0];
    if (idx < 2 * 2 * 4 * kH) hpay[idx] = 0ull;
    if (idx < 2 * 2 * 32 * 256) zpay[idx] = 0ull;
    if (idx < 4) claims[idx] = 0;
    if (idx < 64) prog[idx] = 0;
    for (long r = idx; r < ringN; r += (long)gridDim.x * 256) ring[r] = 0ull;
}

__global__ void k_zero(float* __restrict__ out) {
    int idx = blockIdx.x * 256 + threadIdx.x;
    if (idx < kE) out[idx] = 0.f;
}

// ---------------------------------------------------------------------------
// Producer/consumer recurrent kernel, deadlock-free version.
//   consumers (32/dir, slots 0..31): run the recurrence. Each step they VOTE
//     (block-uniform) on whether the ring entry is stamped; if not, they
//     compute the gate x-projection locally (exact legacy arithmetic). So
//     correctness and forward progress never depend on producers existing.
//   producers (32/dir, slots 32..63): fill the ring R steps deep, pacing off
//     the consumer's progress counter; fast-forward past consumed steps.
// __launch_bounds__(256,2) caps VGPR at 256 -> 2 blocks/CU -> both roles
// co-resident (the round-2 deadlock was VGPR>256 -> producers never launched).
// ---------------------------------------------------------------------------
__global__ __launch_bounds__(256, 2) void k_recur_pc(
    const float* __restrict__ edges,
    const float* __restrict__ Wih_f, const float* __restrict__ b_f,
    const float* __restrict__ Wih_b, const float* __restrict__ b_b,
    const float* __restrict__ Whh_f, const float* __restrict__ Whh_b,
    const float* __restrict__ Wa, const float* __restrict__ ba,
    const float* __restrict__ Wao, const float* __restrict__ bao,
    __hip_bfloat16* __restrict__ arc_f, __hip_bfloat16* __restrict__ arc_b,
    ull* __restrict__ hpay, ull* __restrict__ zpay,
    ull* __restrict__ ring, int* __restrict__ prog, int* __restrict__ claims,
    int Rm) {

    __shared__ int s_role, s_dir, s_b;
    if (threadIdx.x == 0) {
        unsigned xcc = (unsigned)__builtin_amdgcn_s_getreg((31 << 11) | (0 << 6) | 20) & 15u;
        int role = -1, dir = 0, b = 0;
        if (xcc <= 1) {
            int c = atomicAdd(&claims[xcc], 1);
            if (c < 32) { role = 0; dir = (int)xcc; b = c; }
            else if (c < 64) { role = 1; dir = (int)xcc; b = c - 32; }
        } else {
            for (int sl = 0; sl < 64; sl++) __builtin_amdgcn_s_sleep(64);
            for (int dd = 0; dd < 2 && role < 0; dd++) {
                if (__hip_atomic_load(&claims[dd], __ATOMIC_RELAXED,
                                      __HIP_MEMORY_SCOPE_AGENT) < 64) {
                    int c = atomicAdd(&claims[dd], 1);
                    if (c < 32) { role = 0; dir = dd; b = c; }
                    else if (c < 64) { role = 1; dir = dd; b = c - 32; }
                }
            }
        }
        s_role = role; s_dir = dir; s_b = b;
    }
    __syncthreads();
    const int role = s_role;
    if (role < 0) return;
    const int dir = s_dir;
    const int b   = s_b;
    const int tid = threadIdx.x;
    const int d_g = tid >> 6, jl2 = tid & 63;

    // ring geometry (runtime R = Rm+1)
    const size_t ringDir = ((size_t)(Rm + 1)) << 13;     // R * 32 * 256
    ull* __restrict__ rb = ring + (size_t)dir * ringDir;

    __shared__ __align__(16) float hprev_p[4 * 132];
    __shared__ float Mh[4][64];
    __shared__ float cring[4][16];
    __shared__ float harcl[4][16];
    __shared__ float carcl[4][16];
    __shared__ float logit_l[4];
    __shared__ float WaS[64][17];
    __shared__ __align__(16) float x_s[4][256];
    __shared__ float xpart[4][4][64];
    __shared__ int okf[4];
    __shared__ int s_pr;

    // ---------------- producer role ----------------
    if (role == 1) {
        const float* __restrict__ Wih = dir ? Wih_b : Wih_f;
        const float* __restrict__ bia = dir ? b_b : b_f;
        const int Jg2 = (jl2 >> 4) * kH + b * 16 + (jl2 & 15);
        float wih[64];
        {
            const float* wr = Wih + (size_t)Jg2 * kF + d_g * 64;
            #pragma unroll
            for (int kk = 0; kk < 64; kk++) wih[kk] = wr[kk];
        }
        const float biasR = bia[Jg2];
        const int ahead = Rm - 2;        // may produce step s while s <= prog+ahead

        int s = 0;
        while (s < kN) {
            if (tid == 0) {
                int pr = __hip_atomic_load(&prog[dir * 32 + b], __ATOMIC_RELAXED,
                                           __HIP_MEMORY_SCOPE_AGENT);
                while (pr + ahead < s) {
                    __builtin_amdgcn_s_sleep(16);
                    pr = __hip_atomic_load(&prog[dir * 32 + b], __ATOMIC_RELAXED,
                                           __HIP_MEMORY_SCOPE_AGENT);
                }
                s_pr = pr;
            }
            __syncthreads();             // pacing + orders x_s reuse
            {
                int pr = s_pr;
                if (pr > s) s = pr;      // fast-forward past consumed steps
            }
            if (s >= kN) break;

            const int i = dir ? kN - 1 - s : s;
            int row;
            if (dir == 0) row = i * 4 + d_g;
            else { row = (i + 1 + d_g) * 4 + d_g; if (row > kE - 1) row = kE - 1; }
            float4 xv = *(const float4*)(edges + (size_t)row * kF + 4 * jl2);

            *(float4*)(&x_s[d_g][4 * jl2]) = xv;
            __syncthreads();
            float p0 = 0.f, p1 = 0.f, p2 = 0.f, p3 = 0.f;
            #pragma unroll
            for (int k4 = 0; k4 < 16; k4++) {
                float4 a0 = *(const float4*)&x_s[0][d_g * 64 + k4 * 4];
                float4 a1 = *(const float4*)&x_s[1][d_g * 64 + k4 * 4];
                float4 a2 = *(const float4*)&x_s[2][d_g * 64 + k4 * 4];
                float4 a3 = *(const float4*)&x_s[3][d_g * 64 + k4 * 4];
                float w0 = wih[k4*4], w1 = wih[k4*4+1];
                float w2 = wih[k4*4+2], w3 = wih[k4*4+3];
                p0 += w0*a0.x + w1*a0.y + w2*a0.z + w3*a0.w;
                p1 += w0*a1.x + w1*a1.y + w2*a1.z + w3*a1.w;
                p2 += w0*a2.x + w1*a2.y + w2*a2.z + w3*a2.w;
                p3 += w0*a3.x + w1*a3.y + w2*a3.z + w3*a3.w;
            }
            xpart[d_g][0][jl2] = p0; xpart[d_g][1][jl2] = p1;
            xpart[d_g][2][jl2] = p2; xpart[d_g][3][jl2] = p3;
            __syncthreads();
            float val = biasR + xpart[0][d_g][jl2] + xpart[1][d_g][jl2]
                              + xpart[2][d_g][jl2] + xpart[3][d_g][jl2];
            st_pair(rb + (((size_t)(s & Rm) * 32 + b) << 8) + tid, val,
                    (unsigned)(s + 1));
            s++;
        }
        return;
    }

    // ---------------- consumer role ----------------
    const float* __restrict__ Whh = dir ? Whh_b : Whh_f;
    const float* __restrict__ WihC = dir ? Wih_b : Wih_f;
    const float* __restrict__ biaC = dir ? b_b : b_f;
    __hip_bfloat16* __restrict__ arc = dir ? arc_b : arc_f;

    const int jl = tid >> 2, ks = tid & 3;
    const int Jg = (jl >> 4) * kH + b * 16 + (jl & 15);
    const int a_id = jl2;
    const int s3m = jl2 & 15;
    const int Jg2 = (jl2 >> 4) * kH + b * 16 + (jl2 & 15);

    float w[128];
    {
        const float* wr = Whh + (size_t)Jg * kH + ks * 128;
        #pragma unroll
        for (int kk = 0; kk < 128; kk++) w[kk] = wr[kk];
    }
    const float WaoR = Wao[a_id];
    const float baoR = bao[0];
    const float baR  = ba[a_id];
    const float wax0 = Wa[(size_t)a_id * 515 + 512];
    const float wax1 = Wa[(size_t)a_id * 515 + 513];
    const float wax2 = Wa[(size_t)a_id * 515 + 514];

    for (int l2 = tid; l2 < 4 * 132; l2 += 256) hprev_p[l2] = 0.f;
    Mh[tid >> 6][tid & 63] = 0.f;
    if (tid < 64) cring[tid >> 4][tid & 15] = 0.f;
    for (int l2 = tid; l2 < 1024; l2 += 256)
        WaS[l2 >> 4][l2 & 15] = Wa[(size_t)(l2 >> 4) * 515 + b * 16 + (l2 & 15)];
    __syncthreads();

    auto rp = [&](int t) -> ull* {
        return rb + (((size_t)(t & Rm) * 32 + b) << 8) + tid;
    };
    auto erow = [&](int i) -> int {
        int r;
        if (dir == 0) r = i * 4 + d_g;
        else { r = (i + 1 + d_g) * 4 + d_g; if (r > kE - 1) r = kE - 1; }
        return r;
    };

    const int i0 = dir ? kN - 1 : 0;
    ull xq_raw = ld_raw(rp(0));
    float4 exv = *(const float4*)(edges + (size_t)erow(i0) * kF);
    int miss_streak = 0;

    for (int t = 0; t < kN; t++) {
        const int i = dir ? kN - 1 - t : t;
        const unsigned stamp = (unsigned)(t + 1);
        const int par = t & 1;

        // ---- prefetch next step's ring entry + edge head (for zx) ----
        ull xq_nraw;
        float4 exv_n;
        {
            const int tn = (t + 1 < kN) ? t + 1 : t;
            xq_nraw = ld_raw(rp(tn));
            const int nn = dir ? kN - 1 - tn : tn;
            exv_n = *(const float4*)(edges + (size_t)erow(nn) * kF);
        }

        // ---- A: M[iprev] = hprev . Whh^T (own 64 rows) ----
        float acc = 0.f;
        {
            const float* hp = &hprev_p[ks * 132];
            #pragma unroll
            for (int kk = 0; kk < 128; kk += 4) {
                float4 hv = *(const float4*)(hp + kk);
                acc += w[kk] * hv.x + w[kk+1] * hv.y + w[kk+2] * hv.z + w[kk+3] * hv.w;
            }
        }
        acc += __shfl_xor(acc, 1);
        acc += __shfl_xor(acc, 2);
        const int iprev = dir ? i + 1 : i - 1;
        if (ks == 0) Mh[iprev & 3][jl] = acc;

        // ---- ring-entry vote (bounded retry; block-uniform via okf+B1) ----
        bool mine = ((unsigned)(xq_raw >> 32) == stamp);
        if (!mine && miss_streak < 8) {
            #pragma unroll 1
            for (int r = 0; r < 4 && !mine; r++) {
                __builtin_amdgcn_s_sleep(1);
                xq_raw = ld_raw(rp(t));
                mine = ((unsigned)(xq_raw >> 32) == stamp);
            }
        }
        const int wok = __all(mine) ? 1 : 0;
        if ((tid & 63) == 0) okf[d_g] = wok;
        __syncthreads();   // B1: Mh + okf ready
        const bool allok = okf[0] && okf[1] && okf[2] && okf[3];

        float xq;
        if (allok) {
            xq = __uint_as_float((unsigned)xq_raw);
            miss_streak = 0;
        } else {
            // local fallback: exact legacy XFIN arithmetic (weights from L2)
            miss_streak++;
            const float4 xv = *(const float4*)(edges + (size_t)erow(i) * kF + 4 * jl2);
            *(float4*)(&x_s[d_g][4 * jl2]) = xv;
            __syncthreads();
            const float* wr = WihC + (size_t)Jg2 * kF + d_g * 64;
            float p0 = 0.f, p1 = 0.f, p2 = 0.f, p3 = 0.f;
            #pragma unroll
            for (int k4 = 0; k4 < 16; k4++) {
                float4 wv = *(const float4*)(wr + k4 * 4);
                float4 a0 = *(const float4*)&x_s[0][d_g * 64 + k4 * 4];
                float4 a1 = *(const float4*)&x_s[1][d_g * 64 + k4 * 4];
                float4 a2 = *(const float4*)&x_s[2][d_g * 64 + k4 * 4];
                float4 a3 = *(const float4*)&x_s[3][d_g * 64 + k4 * 4];
                p0 += wv.x*a0.x + wv.y*a0.y + wv.z*a0.z + wv.w*a0.w;
                p1 += wv.x*a1.x + wv.y*a1.y + wv.z*a1.z + wv.w*a1.w;
                p2 += wv.x*a2.x + wv.y*a2.y + wv.z*a2.z + wv.w*a2.w;
                p3 += wv.x*a3.x + wv.y*a3.y + wv.z*a3.z + wv.w*a3.w;
            }
            xpart[d_g][0][jl2] = p0; xpart[d_g][1][jl2] = p1;
            xpart[d_g][2][jl2] = p2; xpart[d_g][3][jl2] = p3;
            __syncthreads();
            xq = biaC[Jg2] + xpart[0][d_g][jl2] + xpart[1][d_g][jl2]
                           + xpart[2][d_g][jl2] + xpart[3][d_g][jl2];
        }
        // slot t consumed by all threads -> let the producer advance
        if (tid == 0)
            __hip_atomic_store(&prog[dir * 32 + b], t + 1, __ATOMIC_RELAXED,
                               __HIP_MEMORY_SCOPE_AGENT);

        const float zxv = baR + wax0 * exv.x + wax1 * exv.y + wax2 * exv.z;

        // ---- B: fused per-wave cell (wave = arc, lanes<16) + publish h ----
        const int pp = dir ? i + 1 + d_g : i - 1 - d_g;
        const bool v3 = dir ? (pp < kN) : (pp >= 0);
        const float xi = __shfl(xq, s3m);
        const float xf = __shfl(xq, 16 + s3m);
        const float xg = __shfl(xq, 32 + s3m);
        const float xo = __shfl(xq, 48 + s3m);
        if (jl2 < 16) {
            const int s3 = jl2;
            float gi = xi + Mh[pp & 3][s3];
            float gf = xf + Mh[pp & 3][16 + s3];
            float gg = xg + Mh[pp & 3][32 + s3];
            float go = xo + Mh[pp & 3][48 + s3];
            float cp = cring[pp & 3][s3];
            float c = sigm(gf) * cp + sigm(gi) * tanhf(gg);
            float h = sigm(go) * tanhf(c);
            float hm = v3 ? h : 0.f, cm = v3 ? c : 0.f;
            harcl[d_g][s3] = hm; carcl[d_g][s3] = cm;
            st_pair(hpay + (((dir * 2 + par) * 4 + d_g) << 9) + b * 16 + s3, hm, stamp);
            arc[((size_t)i * 4 + d_g) * kH + b * 16 + s3] = __float2bfloat16(hm);
        }
        // z partial over own 16 h-dims (intra-wave harcl dep -> no barrier)
        {
            float zp = 0.f;
            #pragma unroll
            for (int ss = 0; ss < 16; ss++) zp += WaS[a_id][ss] * harcl[d_g][ss];
            st_pair(zpay + (((dir * 2 + par) * 32 + b) << 8) + tid, zp, stamp);
        }

        // ---- E: batched stamped loads, legacy z-spin then h-spin ----
        const ull* zb = zpay + (((size_t)(dir * 2 + par) * 32) << 8) + tid;
        ull zv_[32];
        #pragma unroll
        for (int bb = 0; bb < 32; bb++) zv_[bb] = ld_raw(zb + ((size_t)bb << 8));
        const ull* hb = hpay + (((size_t)(dir * 2 + par) * 4) << 9);
        ull hv_[8];
        #pragma unroll
        for (int dd = 0; dd < 4; dd++) {
            hv_[2*dd]   = ld_raw(hb + (dd << 9) + 2 * tid);
            hv_[2*dd+1] = ld_raw(hb + (dd << 9) + 2 * tid + 1);
        }

        for (;;) {
            bool ok = true;
            #pragma unroll
            for (int bb = 0; bb < 32; bb++)
                ok &= ((unsigned)(zv_[bb] >> 32) == stamp);
            if (ok) break;
            __builtin_amdgcn_s_sleep(2);
            #pragma unroll
            for (int bb = 0; bb < 32; bb++)
                if ((unsigned)(zv_[bb] >> 32) != stamp)
                    zv_[bb] = ld_raw(zb + ((size_t)bb << 8));
        }
        float zsum = 0.f;
        #pragma unroll
        for (int bb = 0; bb < 32; bb++) zsum += __uint_as_float((unsigned)zv_[bb]);

        for (;;) {
            bool ok = true;
            #pragma unroll
            for (int q = 0; q < 8; q++)
                ok &= ((unsigned)(hv_[q] >> 32) == stamp);
            if (ok) break;
            __builtin_amdgcn_s_sleep(2);
            #pragma unroll
            for (int dd = 0; dd < 4; dd++) {
                if ((unsigned)(hv_[2*dd]   >> 32) != stamp) hv_[2*dd]   = ld_raw(hb + (dd << 9) + 2 * tid);
                if ((unsigned)(hv_[2*dd+1] >> 32) != stamp) hv_[2*dd+1] = ld_raw(hb + (dd << 9) + 2 * tid + 1);
            }
        }

        float zv = fmaxf(zsum + zxv, 0.f);
        float lv = WaoR * zv;
        #pragma unroll
        for (int o2 = 1; o2 < 64; o2 <<= 1) lv += __shfl_xor(lv, o2);
        if (a_id == 0) {
            logit_l[d_g] = v3 ? tanhf(lv + baoR) : -1e9f;
        }
        __syncthreads();   // B4: logits ready

        float l0 = logit_l[0], l1 = logit_l[1], l2 = logit_l[2], l3 = logit_l[3];
        float mx = fmaxf(fmaxf(l0, l1), fmaxf(l2, l3));
        float e0 = __expf(l0 - mx), e1 = __expf(l1 - mx);
        float e2 = __expf(l2 - mx), e3 = __expf(l3 - mx);
        float inv = 1.f / (e0 + e1 + e2 + e3);
        float wg[4] = { e0 * inv, e1 * inv, e2 * inv, e3 * inv };

        float hn0 = 0.f, hn1 = 0.f;
        #pragma unroll
        for (int dd = 0; dd < 4; dd++) {
            hn0 += wg[dd] * __uint_as_float((unsigned)hv_[2*dd]);
            hn1 += wg[dd] * __uint_as_float((unsigned)hv_[2*dd+1]);
        }
        {
            const int g = 2 * tid;
            const int ch = g >> 7, wi = g & 127;
            hprev_p[ch * 132 + wi]     = hn0;
            hprev_p[ch * 132 + wi + 1] = hn1;
        }
        if (tid < 16) {
            float cn = wg[0] * carcl[0][tid] + wg[1] * carcl[1][tid]
                     + wg[2] * carcl[2][tid] + wg[3] * carcl[3][tid];
            cring[i & 3][tid] = cn;
        }
        __syncthreads();   // B5: hprev/cring ready for next step

        xq_raw = xq_nraw;
        exv = exv_n;
    }
}

// ---------------------------------------------------------------------------
// Legacy recurrent kernel (in-loop xproj) — fallback when ws can't hold even a
// minimal ring. Verbatim round-11 structure (45.6 ms).
// ---------------------------------------------------------------------------
__global__ __launch_bounds__(256, 1) void k_recur_legacy(
    const float* __restrict__ edges,
    const float* __restrict__ Wih_f, const float* __restrict__ Whh_f, const float* __restrict__ b_f,
    const float* __restrict__ Wih_b, const float* __restrict__ Whh_b, const float* __restrict__ b_b,
    const float* __restrict__ Wa, const float* __restrict__ ba,
    const float* __restrict__ Wao, const float* __restrict__ bao,
    __hip_bfloat16* __restrict__ arc_f, __hip_bfloat16* __restrict__ arc_b,
    ull* __restrict__ hpay, ull* __restrict__ zpay, int* __restrict__ claims) {

    __shared__ int s_slot;
    if (threadIdx.x == 0) {
        unsigned xcc = (unsigned)__builtin_amdgcn_s_getreg((31 << 11) | (0 << 6) | 20) & 15u;
        int slot = -1;
        if (xcc <= 1) {
            int c = atomicAdd(&claims[xcc], 1);
            if (c < 32) slot = (int)xcc * 32 + c;
        } else {
            for (int sl = 0; sl < 64; sl++) __builtin_amdgcn_s_sleep(64);
            for (int dd = 0; dd < 2 && slot < 0; dd++) {
                if (__hip_atomic_load(&claims[dd], __ATOMIC_RELAXED,
                                      __HIP_MEMORY_SCOPE_AGENT) < 32) {
                    int c = atomicAdd(&claims[dd], 1);
                    if (c < 32) slot = dd * 32 + c;
                }
            }
        }
        s_slot = slot;
    }
    __syncthreads();
    const int slot = s_slot;
    if (slot < 0) return;
    const int dir = slot >> 5;
    const int b   = slot & 31;

    const float* __restrict__ Whh = dir ? Whh_b : Whh_f;
    const float* __restrict__ Wih = dir ? Wih_b : Wih_f;
    const float* __restrict__ bia = dir ? b_b  : b_f;
    __hip_bfloat16* __restrict__ arc = dir ? arc_b : arc_f;
    const int tid = threadIdx.x;

    const int jl = tid >> 2, ks = tid & 3;
    const int Jg = (jl >> 4) * kH + b * 16 + (jl & 15);
    const int d_g = tid >> 6, jl2 = tid & 63;
    const int Jg2 = (jl2 >> 4) * kH + b * 16 + (jl2 & 15);
    const int a_id = jl2;

    float w[128];
    {
        const float* wr = Whh + (size_t)Jg * kH + ks * 128;
        #pragma unroll
        for (int kk = 0; kk < 128; kk++) w[kk] = wr[kk];
    }
    float wih[64];
    {
        const float* wr = Wih + (size_t)Jg2 * kF + d_g * 64;
        #pragma unroll
        for (int kk = 0; kk < 64; kk++) wih[kk] = wr[kk];
    }
    const float biasR = bia[Jg2];
    const float baR   = ba[a_id];
    const float WaoR  = Wao[a_id];
    const float baoR  = bao[0];
    const float wax0  = Wa[(size_t)a_id * 515 + 512];
    const float wax1  = Wa[(size_t)a_id * 515 + 513];
    const float wax2  = Wa[(size_t)a_id * 515 + 514];

    __shared__ __align__(16) float hprev_p[4 * 132];
    __shared__ float Mh[4][64];
    __shared__ float cring[4][16];
    __shared__ float harcl[4][16];
    __shared__ float carcl[4][16];
    __shared__ float logit_l[4];
    __shared__ float WaS[64][17];
    __shared__ float xpl[2][4][64];
    __shared__ __align__(16) float x_s[4][256];
    __shared__ float xpart[4][4][64];

    for (int l2 = tid; l2 < 4 * 132; l2 += 256) hprev_p[l2] = 0.f;
    Mh[tid >> 6][tid & 63] = 0.f;
    if (tid < 64) cring[tid >> 4][tid & 15] = 0.f;
    for (int l2 = tid; l2 < 1024; l2 += 256)
        WaS[l2 >> 4][l2 & 15] = Wa[(size_t)(l2 >> 4) * 515 + b * 16 + (l2 & 15)];
    __syncthreads();

#define XLOAD(nn, XV) do {                                                    \
        int row_;                                                             \
        if (dir == 0) row_ = (nn) * 4 + d_g;                                  \
        else { row_ = ((nn) + 1 + d_g) * 4 + d_g;                             \
               if (row_ > kE - 1) row_ = kE - 1; }                            \
        XV = *(const float4*)(edges + (size_t)row_ * kF + 4 * jl2);           \
    } while (0)

#define XFIN(XV, BUF, ZXOUT) do {                                             \
        *(float4*)(&x_s[d_g][4 * jl2]) = XV;                                  \
        __syncthreads();                                                      \
        float p0_ = 0.f, p1_ = 0.f, p2_ = 0.f, p3_ = 0.f;                     \
        _Pragma("unroll")                                                     \
        for (int k4_ = 0; k4_ < 16; k4_++) {                                  \
            float4 a0_ = *(const float4*)&x_s[0][d_g * 64 + k4_ * 4];         \
            float4 a1_ = *(const float4*)&x_s[1][d_g * 64 + k4_ * 4];         \
            float4 a2_ = *(const float4*)&x_s[2][d_g * 64 + k4_ * 4];         \
            float4 a3_ = *(const float4*)&x_s[3][d_g * 64 + k4_ * 4];         \
            float w0_ = wih[k4_*4], w1_ = wih[k4_*4+1];                       \
            float w2_ = wih[k4_*4+2], w3_ = wih[k4_*4+3];                     \
            p0_ += w0_*a0_.x + w1_*a0_.y + w2_*a0_.z + w3_*a0_.w;             \
            p1_ += w0_*a1_.x + w1_*a1_.y + w2_*a1_.z + w3_*a1_.w;             \
            p2_ += w0_*a2_.x + w1_*a2_.y + w2_*a2_.z + w3_*a2_.w;             \
            p3_ += w0_*a3_.x + w1_*a3_.y + w2_*a3_.z + w3_*a3_.w;             \
        }                                                                     \
        xpart[d_g][0][jl2] = p0_; xpart[d_g][1][jl2] = p1_;                   \
        xpart[d_g][2][jl2] = p2_; xpart[d_g][3][jl2] = p3_;                   \
        __syncthreads();                                                      \
        xpl[BUF][d_g][jl2] = biasR + xpart[0][d_g][jl2] + xpart[1][d_g][jl2]  \
                                   + xpart[2][d_g][jl2] + xpart[3][d_g][jl2]; \
        ZXOUT = baR + wax0 * x_s[d_g][0] + wax1 * x_s[d_g][1]                 \
                    + wax2 * x_s[d_g][2];                                     \
    } while (0)

    const int i0 = dir ? kN - 1 : 0;
    float zxv, zx_n;
    {
        float4 xv0;
        XLOAD(i0, xv0);
        XFIN(xv0, 0, zxv);
    }
    __syncthreads();

    for (int t = 0; t < kN; t++) {
        const int i = dir ? kN - 1 - t : t;
        const unsigned stamp = (unsigned)(t + 1);
        const int par = t & 1;

        float4 xv_n;
        {
            const int nn = (t + 1 < kN) ? (dir ? i - 1 : i + 1) : i;
            XLOAD(nn, xv_n);
        }

        float acc = 0.f;
        {
            const float* hp = &hprev_p[ks * 132];
            #pragma unroll
            for (int kk = 0; kk < 128; kk += 4) {
                float4 hv = *(const float4*)(hp + kk);
                acc += w[kk] * hv.x + w[kk+1] * hv.y + w[kk+2] * hv.z + w[kk+3] * hv.w;
            }
        }
        acc += __shfl_xor(acc, 1);
        acc += __shfl_xor(acc, 2);
        const int iprev = dir ? i + 1 : i - 1;
        if (ks == 0) Mh[iprev & 3][jl] = acc;
        __syncthreads();

        const int pp = dir ? i + 1 + d_g : i - 1 - d_g;
        const bool v3 = dir ? (pp < kN) : (pp >= 0);
        if (jl2 < 16) {
            const int s3 = jl2;
            float gi = xpl[par][d_g][s3]      + Mh[pp & 3][s3];
            float gf = xpl[par][d_g][16 + s3] + Mh[pp & 3][16 + s3];
            float gg = xpl[par][d_g][32 + s3] + Mh[pp & 3][32 + s3];
            float go = xpl[par][d_g][48 + s3] + Mh[pp & 3][48 + s3];
            float cp = cring[pp & 3][s3];
            float c = sigm(gf) * cp + sigm(gi) * tanhf(gg);
            float h = sigm(go) * tanhf(c);
            float hm = v3 ? h : 0.f, cm = v3 ? c : 0.f;
            harcl[d_g][s3] = hm; carcl[d_g][s3] = cm;
            st_pair(hpay + (((dir * 2 + par) * 4 + d_g) << 9) + b * 16 + s3, hm, stamp);
            arc[((size_t)i * 4 + d_g) * kH + b * 16 + s3] = __float2bfloat16(hm);
        }
        {
            float zp = 0.f;
            #pragma unroll
            for (int ss = 0; ss < 16; ss++) zp += WaS[a_id][ss] * harcl[d_g][ss];
            st_pair(zpay + (((dir * 2 + par) * 32 + b) << 8) + tid, zp, stamp);
        }

        float xp_dummy; (void)xp_dummy;
        XFIN(xv_n, par ^ 1, zx_n);

        const ull* zb = zpay + (((size_t)(dir * 2 + par) * 32) << 8) + tid;
        ull zv_[32];
        #pragma unroll
        for (int bb = 0; bb < 32; bb++) zv_[bb] = ld_raw(zb + ((size_t)bb << 8));
        const ull* hb = hpay + (((size_t)(dir * 2 + par) * 4) << 9);
        ull hv_[8];
        #pragma unroll
        for (int dd = 0; dd < 4; dd++) {
            hv_[2*dd]   = ld_raw(hb + (dd << 9) + 2 * tid);
            hv_[2*dd+1] = ld_raw(hb + (dd << 9) + 2 * tid + 1);
        }

        for (;;) {
            bool ok = true;
            #pragma unroll
            for (int bb = 0; bb < 32; bb++)
                ok &= ((unsigned)(zv_[bb] >> 32) == stamp);
            if (ok) break;
            __builtin_amdgcn_s_sleep(2);
            #pragma unroll
            for (int bb = 0; bb < 32; bb++)
                if ((unsigned)(zv_[bb] >> 32) != stamp)
                    zv_[bb] = ld_raw(zb + ((size_t)bb << 8));
        }
        float zsum = 0.f;
        #pragma unroll
        for (int bb = 0; bb < 32; bb++) zsum += __uint_as_float((unsigned)zv_[bb]);

        for (;;) {
            bool ok = true;
            #pragma unroll
            for (int q = 0; q < 8; q++)
                ok &= ((unsigned)(hv_[q] >> 32) == stamp);
            if (ok) break;
            __builtin_amdgcn_s_sleep(2);
            #pragma unroll
            for (int dd = 0; dd < 4; dd++) {
                if ((unsigned)(hv_[2*dd]   >> 32) != stamp) hv_[2*dd]   = ld_raw(hb + (dd << 9) + 2 * tid);
                if ((unsigned)(hv_[2*dd+1] >> 32) != stamp) hv_[2*dd+1] = ld_raw(hb + (dd << 9) + 2 * tid + 1);
            }
        }

        float zv = fmaxf(zsum + zxv, 0.f);
        float lv = WaoR * zv;
        #pragma unroll
        for (int o2 = 1; o2 < 64; o2 <<= 1) lv += __shfl_xor(lv, o2);
        if (a_id == 0) {
            logit_l[d_g] = v3 ? tanhf(lv + baoR) : -1e9f;
        }
        __syncthreads();

        float l0 = logit_l[0], l1 = logit_l[1], l2 = logit_l[2], l3 = logit_l[3];
        float mx = fmaxf(fmaxf(l0, l1), fmaxf(l2, l3));
        float e0 = __expf(l0 - mx), e1 = __expf(l1 - mx);
        float e2 = __expf(l2 - mx), e3 = __expf(l3 - mx);
        float inv = 1.f / (e0 + e1 + e2 + e3);
        float wg[4] = { e0 * inv, e1 * inv, e2 * inv, e3 * inv };

        float hn0 = 0.f, hn1 = 0.f;
        #pragma unroll
        for (int dd = 0; dd < 4; dd++) {
            hn0 += wg[dd] * __uint_as_float((unsigned)hv_[2*dd]);
            hn1 += wg[dd] * __uint_as_float((unsigned)hv_[2*dd+1]);
        }
        {
            const int g = 2 * tid;
            const int ch = g >> 7, wi = g & 127;
            hprev_p[ch * 132 + wi]     = hn0;
            hprev_p[ch * 132 + wi + 1] = hn1;
        }
        if (tid < 16) {
            float cn = wg[0] * carcl[0][tid] + wg[1] * carcl[1][tid]
                     + wg[2] * carcl[2][tid] + wg[3] * carcl[3][tid];
            cring[i & 3][tid] = cn;
        }
        __syncthreads();

        zxv = zx_n;
    }
#undef XLOAD
#undef XFIN
}

// ---------------------------------------------------------------------------
// decoder: out[e] += sum_l Wdo[l] * relu(bd[l] + sum_k Wd[l,k] feat[e,k])
// ---------------------------------------------------------------------------
__global__ __launch_bounds__(256) void k_dec(
    const __hip_bfloat16* __restrict__ arc_f, const __hip_bfloat16* __restrict__ arc_b,
    const float* __restrict__ Wd, const float* __restrict__ bd,
    const float* __restrict__ Wdo, float* __restrict__ out) {
    const int e0 = blockIdx.x * 128;
    const int l0 = blockIdx.y * 128;
    __shared__ __align__(16) float As[8][128];
    __shared__ __align__(16) float Bs[8][128];
    const int tid = threadIdx.x;
    const int tx = tid & 15, ty = tid >> 4;
    const int lr = tid & 127, kq = tid >> 7;

    const int e = e0 + lr;
    const int j = e >> 2, d = e & 3;
    const int jb = j - 1 - d;
    const __hip_bfloat16* frow  = arc_f + (size_t)e * kH;
    const __hip_bfloat16* brow2 = (jb >= 0) ? (arc_b + ((size_t)jb * 4 + d) * kH) : nullptr;
    const float* wrow = Wd + (size_t)(l0 + lr) * (2 * kH);

    float acc[8][8] = {};
    for (int k0 = 0; k0 < 2 * kH; k0 += 8) {
        const int kk = k0 + kq * 4;
        float4 av4;
        if (kk < kH) av4 = ld_bf4(frow + kk);
        else if (brow2) av4 = ld_bf4(brow2 + (kk - kH));
        else av4 = make_float4(0.f, 0.f, 0.f, 0.f);
        float4 bv4 = *(const float4*)(wrow + kk);
        __syncthreads();
        As[kq*4+0][lr] = av4.x; As[kq*4+1][lr] = av4.y;
        As[kq*4+2][lr] = av4.z; As[kq*4+3][lr] = av4.w;
        Bs[kq*4+0][lr] = bv4.x; Bs[kq*4+1][lr] = bv4.y;
        Bs[kq*4+2][lr] = bv4.z; Bs[kq*4+3][lr] = bv4.w;
        __syncthreads();
        #pragma unroll
        for (int kt = 0; kt < 8; kt++) {
            __align__(16) float a0[8], b0[8];
            *(float4*)&a0[0] = *(const float4*)&As[kt][ty*8];
            *(float4*)&a0[4] = *(const float4*)&As[kt][ty*8+4];
            *(float4*)&b0[0] = *(const float4*)&Bs[kt][tx*8];
            *(float4*)&b0[4] = *(const float4*)&Bs[kt][tx*8+4];
            #pragma unroll
            for (int mi = 0; mi < 8; mi++)
                #pragma unroll
                for (int ni = 0; ni < 8; ni++)
                    acc[mi][ni] += a0[mi] * b0[ni];
        }
    }
    #pragma unroll
    for (int mi = 0; mi < 8; mi++) {
        float sacc = 0.f;
        #pragma unroll
        for (int ni = 0; ni < 8; ni++) {
            int l = l0 + tx * 8 + ni;
            sacc += Wdo[l] * fmaxf(acc[mi][ni] + bd[l], 0.f);
        }
        sacc += __shfl_xor(sacc, 1);
        sacc += __shfl_xor(sacc, 2);
        sacc += __shfl_xor(sacc, 4);
        sacc += __shfl_xor(sacc, 8);
        if (tx == 0) atomicAdd(out + e0 + ty * 8 + mi, sacc);
    }
}

// ---------------------------------------------------------------------------
extern "C" void kernel_launch(void* const* d_in, const int* in_sizes, int n_in,
                              void* d_out, int out_size, void* d_ws, size_t ws_size,
                              hipStream_t stream) {
    const float* edges = (const float*)d_in[0];
    const float* Wih_f = (const float*)d_in[1];
    const float* Whh_f = (const float*)d_in[2];
    const float* b_f   = (const float*)d_in[3];
    const float* Wih_b = (const float*)d_in[4];
    const float* Whh_b = (const float*)d_in[5];
    const float* b_b   = (const float*)d_in[6];
    const float* Wa    = (const float*)d_in[7];
    const float* ba    = (const float*)d_in[8];
    const float* Wao   = (const float*)d_in[9];
    const float* bao   = (const float*)d_in[10];
    const float* Wd    = (const float*)d_in[11];
    const float* bd    = (const float*)d_in[12];
    const float* Wdo   = (const float*)d_in[13];
    const float* bdo   = (const float*)d_in[14];
    float* out = (float*)d_out;

    char* ws = (char*)d_ws;
    size_t off = 0;
    __hip_bfloat16* arc_f = (__hip_bfloat16*)(ws + off); off += (size_t)kE * kH * 2;  // 33.5 MB
    __hip_bfloat16* arc_b = (__hip_bfloat16*)(ws + off); off += (size_t)kE * kH * 2;  // 33.5 MB
    ull* hpay = (ull*)(ws + off); off += (size_t)2 * 2 * 4 * kH * 8;                  // 128 KB
    ull* zpay = (ull*)(ws + off); off += (size_t)2 * 2 * 32 * 256 * 8;                // 256 KB
    int* claims = (int*)(ws + off); off += 256;
    int* prog   = (int*)(ws + off); off += 256;
    const size_t base = off;

    if (ws_size < base) {
        hipLaunchKernelGGL(k_zero, dim3((kE + 255) / 256), dim3(256), 0, stream, out);
        return;
    }

    // ring: R steps x 2 dirs x 32 b-slots x 256 payloads x 8 B = R * 128 KiB
    int R = 0;
    for (int cand = 128; cand >= 16; cand >>= 1)
        if (base + (size_t)cand * 131072 <= ws_size) { R = cand; break; }

    if (R > 0) {
        ull* ring = (ull*)(ws + base);
        const long ringN = (long)R * 16384;   // total ull entries (2 dirs)
        hipLaunchKernelGGL(k_init, dim3(512), dim3(256), 0, stream,
                           out, bdo, hpay, zpay, claims, prog, ring, ringN);
        hipLaunchKernelGGL(k_recur_pc, dim3(512), dim3(256), 0, stream,
                           edges, Wih_f, b_f, Wih_b, b_b, Whh_f, Whh_b,
                           Wa, ba, Wao, bao, arc_f, arc_b,
                           hpay, zpay, ring, prog, claims, R - 1);
    } else {
        hipLaunchKernelGGL(k_init, dim3(512), dim3(256), 0, stream,
                           out, bdo, hpay, zpay, claims, prog, hpay, 0L);
        hipLaunchKernelGGL(k_recur_legacy, dim3(512), dim3(256), 0, stream,
                           edges, Wih_f, Whh_f, b_f, Wih_b, Whh_b, b_b,
                           Wa, ba, Wao, bao, arc_f, arc_b, hpay, zpay, claims);
    }

    hipLaunchKernelGGL(k_dec, dim3(kE / 128, kL / 128), dim3(256), 0, stream,
                       arc_f, arc_b, Wd, bd, Wdo, out);
}

// Round 4
// 51854.254 us; speedup vs baseline: 3.1837x; 3.1837x over previous
//
#include <hip/hip_runtime.h>
#include <hip/hip_bf16.h>

// Problem constants
constexpr int kN = 8192;
constexpr int kF = 256;
constexpr int kH = 512;
constexpr int kL = 512;
constexpr int kE = kN * 4;           // 32768 edges

using ull = unsigned long long;

__device__ __forceinline__ float sigm(float x) { return 1.f / (1.f + __expf(-x)); }

__device__ __forceinline__ float4 ld_bf4(const __hip_bfloat16* p) {
    uint2 u = *(const uint2*)p;
    float4 r;
    r.x = __uint_as_float(u.x << 16);
    r.y = __uint_as_float(u.x & 0xffff0000u);
    r.z = __uint_as_float(u.y << 16);
    r.w = __uint_as_float(u.y & 0xffff0000u);
    return r;
}

// stamped 8-byte pair: low = float bits, high = stamp (step+1)
__device__ __forceinline__ void st_pair(ull* p, float v, unsigned stamp) {
    ull u = ((ull)stamp << 32) | (ull)__float_as_uint(v);
    __hip_atomic_store(p, u, __ATOMIC_RELAXED, __HIP_MEMORY_SCOPE_AGENT);
}
__device__ __forceinline__ ull ld_raw(const ull* p) {
    return __hip_atomic_load(p, __ATOMIC_RELAXED, __HIP_MEMORY_SCOPE_AGENT);
}

// ---------------------------------------------------------------------------
__global__ void k_init(float* __restrict__ out, const float* __restrict__ bdo,
                       ull* __restrict__ hpay, ull* __restrict__ zpay,
                       int* __restrict__ claims, int* __restrict__ prog,
                       ull* __restrict__ ring, long ringN) {
    int idx = blockIdx.x * 256 + threadIdx.x;
    if (idx < kE) out[idx] = bdo[0];
    if (idx < 2 * 2 * 4 * kH) hpay[idx] = 0ull;
    if (idx < 2 * 2 * 32 * 256) zpay[idx] = 0ull;
    if (idx < 4) claims[idx] = 0;
    if (idx < 64) prog[idx] = 0;
    for (long r = idx; r < ringN; r += (long)gridDim.x * 256) ring[r] = 0ull;
}

__global__ void k_zero(float* __restrict__ out) {
    int idx = blockIdx.x * 256 + threadIdx.x;
    if (idx < kE) out[idx] = 0.f;
}

// ---------------------------------------------------------------------------
// Producer/consumer recurrent kernel, XCD-placement co-residency version.
// Roles by XCD at 1 block/CU (256 resident blocks >> 128 working blocks):
//   xcc0: consumers dir0   xcc1: consumers dir1   (32 each)
//   xcc2: producers dir0   xcc3: producers dir1   (32 each)
// launch_bounds(256,1): the declaration under which this consumer body
// compiles to ~232 VGPR spill-free (round-3's (256,2) spilled w[128] to
// scratch -> FETCH 25 GB, 3.6x regression).
// Consumers vote per step on ring validity; on miss they compute the gate
// x-projection locally (exact legacy arithmetic) -> no producer dependency.
// ---------------------------------------------------------------------------
__global__ __launch_bounds__(256, 1) void k_recur_pc(
    const float* __restrict__ edges,
    const float* __restrict__ Wih_f, const float* __restrict__ b_f,
    const float* __restrict__ Wih_b, const float* __restrict__ b_b,
    const float* __restrict__ Whh_f, const float* __restrict__ Whh_b,
    const float* __restrict__ Wa, const float* __restrict__ ba,
    const float* __restrict__ Wao, const float* __restrict__ bao,
    __hip_bfloat16* __restrict__ arc_f, __hip_bfloat16* __restrict__ arc_b,
    ull* __restrict__ hpay, ull* __restrict__ zpay,
    ull* __restrict__ ring, int* __restrict__ prog, int* __restrict__ claims,
    int Rm) {

    __shared__ int s_role, s_dir, s_b;
    if (threadIdx.x == 0) {
        unsigned xcc = (unsigned)__builtin_amdgcn_s_getreg((31 << 11) | (0 << 6) | 20) & 15u;
        int role = -1, dir = 0, b = 0;
        if (xcc < 4) {
            int c = atomicAdd(&claims[xcc], 1);
            if (c < 32) { role = (int)(xcc >> 1); dir = (int)(xcc & 1); b = c; }
        }
        if (role < 0) {
            for (int sl = 0; sl < 64; sl++) __builtin_amdgcn_s_sleep(64);
            for (int p = 0; p < 4 && role < 0; p++) {
                if (__hip_atomic_load(&claims[p], __ATOMIC_RELAXED,
                                      __HIP_MEMORY_SCOPE_AGENT) < 32) {
                    int c = atomicAdd(&claims[p], 1);
                    if (c < 32) { role = p >> 1; dir = p & 1; b = c; }
                }
            }
        }
        s_role = role; s_dir = dir; s_b = b;
    }
    __syncthreads();
    const int role = s_role;
    if (role < 0) return;
    const int dir = s_dir;
    const int b   = s_b;
    const int tid = threadIdx.x;
    const int d_g = tid >> 6, jl2 = tid & 63;

    // ring geometry (runtime R = Rm+1)
    const size_t ringDir = ((size_t)(Rm + 1)) << 13;     // R * 32 * 256
    ull* __restrict__ rb = ring + (size_t)dir * ringDir;

    __shared__ __align__(16) float hprev_p[4 * 132];
    __shared__ float Mh[4][64];
    __shared__ float cring[4][16];
    __shared__ float harcl[4][16];
    __shared__ float carcl[4][16];
    __shared__ float logit_l[4];
    __shared__ float WaS[64][17];
    __shared__ __align__(16) float x_s[4][256];
    __shared__ float xpart[4][4][64];
    __shared__ int okf[4];
    __shared__ int s_pr;

    // ---------------- producer role ----------------
    if (role == 1) {
        const float* __restrict__ Wih = dir ? Wih_b : Wih_f;
        const float* __restrict__ bia = dir ? b_b : b_f;
        const int Jg2 = (jl2 >> 4) * kH + b * 16 + (jl2 & 15);
        float wih[64];
        {
            const float* wr = Wih + (size_t)Jg2 * kF + d_g * 64;
            #pragma unroll
            for (int kk = 0; kk < 64; kk++) wih[kk] = wr[kk];
        }
        const float biasR = bia[Jg2];
        const int ahead = Rm - 2;        // may produce step s while s <= prog+ahead

        int s = 0;
        while (s < kN) {
            if (tid == 0) {
                int pr = __hip_atomic_load(&prog[dir * 32 + b], __ATOMIC_RELAXED,
                                           __HIP_MEMORY_SCOPE_AGENT);
                while (pr + ahead < s) {
                    __builtin_amdgcn_s_sleep(16);
                    pr = __hip_atomic_load(&prog[dir * 32 + b], __ATOMIC_RELAXED,
                                           __HIP_MEMORY_SCOPE_AGENT);
                }
                s_pr = pr;
            }
            __syncthreads();             // pacing + orders x_s/xpart reuse
            {
                int pr = s_pr;
                if (pr > s) s = pr;      // fast-forward past consumed steps
            }
            if (s >= kN) break;

            const int i = dir ? kN - 1 - s : s;
            int row;
            if (dir == 0) row = i * 4 + d_g;
            else { row = (i + 1 + d_g) * 4 + d_g; if (row > kE - 1) row = kE - 1; }
            float4 xv = *(const float4*)(edges + (size_t)row * kF + 4 * jl2);

            *(float4*)(&x_s[d_g][4 * jl2]) = xv;
            __syncthreads();
            float p0 = 0.f, p1 = 0.f, p2 = 0.f, p3 = 0.f;
            #pragma unroll
            for (int k4 = 0; k4 < 16; k4++) {
                float4 a0 = *(const float4*)&x_s[0][d_g * 64 + k4 * 4];
                float4 a1 = *(const float4*)&x_s[1][d_g * 64 + k4 * 4];
                float4 a2 = *(const float4*)&x_s[2][d_g * 64 + k4 * 4];
                float4 a3 = *(const float4*)&x_s[3][d_g * 64 + k4 * 4];
                float w0 = wih[k4*4], w1 = wih[k4*4+1];
                float w2 = wih[k4*4+2], w3 = wih[k4*4+3];
                p0 += w0*a0.x + w1*a0.y + w2*a0.z + w3*a0.w;
                p1 += w0*a1.x + w1*a1.y + w2*a1.z + w3*a1.w;
                p2 += w0*a2.x + w1*a2.y + w2*a2.z + w3*a2.w;
                p3 += w0*a3.x + w1*a3.y + w2*a3.z + w3*a3.w;
            }
            xpart[d_g][0][jl2] = p0; xpart[d_g][1][jl2] = p1;
            xpart[d_g][2][jl2] = p2; xpart[d_g][3][jl2] = p3;
            __syncthreads();
            float val = biasR + xpart[0][d_g][jl2] + xpart[1][d_g][jl2]
                              + xpart[2][d_g][jl2] + xpart[3][d_g][jl2];
            st_pair(rb + (((size_t)(s & Rm) * 32 + b) << 8) + tid, val,
                    (unsigned)(s + 1));
            s++;
        }
        return;
    }

    // ---------------- consumer role ----------------
    const float* __restrict__ Whh = dir ? Whh_b : Whh_f;
    const float* __restrict__ WihC = dir ? Wih_b : Wih_f;
    const float* __restrict__ biaC = dir ? b_b : b_f;
    __hip_bfloat16* __restrict__ arc = dir ? arc_b : arc_f;

    const int jl = tid >> 2, ks = tid & 3;
    const int Jg = (jl >> 4) * kH + b * 16 + (jl & 15);
    const int a_id = jl2;
    const int s3m = jl2 & 15;
    const int Jg2 = (jl2 >> 4) * kH + b * 16 + (jl2 & 15);

    float w[128];
    {
        const float* wr = Whh + (size_t)Jg * kH + ks * 128;
        #pragma unroll
        for (int kk = 0; kk < 128; kk++) w[kk] = wr[kk];
    }
    const float WaoR = Wao[a_id];
    const float baoR = bao[0];
    const float baR  = ba[a_id];
    const float wax0 = Wa[(size_t)a_id * 515 + 512];
    const float wax1 = Wa[(size_t)a_id * 515 + 513];
    const float wax2 = Wa[(size_t)a_id * 515 + 514];

    for (int l2 = tid; l2 < 4 * 132; l2 += 256) hprev_p[l2] = 0.f;
    Mh[tid >> 6][tid & 63] = 0.f;
    if (tid < 64) cring[tid >> 4][tid & 15] = 0.f;
    for (int l2 = tid; l2 < 1024; l2 += 256)
        WaS[l2 >> 4][l2 & 15] = Wa[(size_t)(l2 >> 4) * 515 + b * 16 + (l2 & 15)];
    __syncthreads();

    auto rp = [&](int t) -> ull* {
        return rb + (((size_t)(t & Rm) * 32 + b) << 8) + tid;
    };
    auto erow = [&](int i) -> int {
        int r;
        if (dir == 0) r = i * 4 + d_g;
        else { r = (i + 1 + d_g) * 4 + d_g; if (r > kE - 1) r = kE - 1; }
        return r;
    };

    const int i0 = dir ? kN - 1 : 0;
    ull xq_raw = ld_raw(rp(0));
    float4 exv = *(const float4*)(edges + (size_t)erow(i0) * kF);
    int miss_streak = 0;

    for (int t = 0; t < kN; t++) {
        const int i = dir ? kN - 1 - t : t;
        const unsigned stamp = (unsigned)(t + 1);
        const int par = t & 1;

        // ---- prefetch next step's ring entry + edge head (for zx) ----
        ull xq_nraw;
        float4 exv_n;
        {
            const int tn = (t + 1 < kN) ? t + 1 : t;
            xq_nraw = ld_raw(rp(tn));
            const int nn = dir ? kN - 1 - tn : tn;
            exv_n = *(const float4*)(edges + (size_t)erow(nn) * kF);
        }

        // ---- A: M[iprev] = hprev . Whh^T (own 64 rows) ----
        float acc = 0.f;
        {
            const float* hp = &hprev_p[ks * 132];
            #pragma unroll
            for (int kk = 0; kk < 128; kk += 4) {
                float4 hv = *(const float4*)(hp + kk);
                acc += w[kk] * hv.x + w[kk+1] * hv.y + w[kk+2] * hv.z + w[kk+3] * hv.w;
            }
        }
        acc += __shfl_xor(acc, 1);
        acc += __shfl_xor(acc, 2);
        const int iprev = dir ? i + 1 : i - 1;
        if (ks == 0) Mh[iprev & 3][jl] = acc;

        // ---- ring-entry vote (bounded retry; block-uniform via okf+B1) ----
        bool mine = ((unsigned)(xq_raw >> 32) == stamp);
        if (!mine && miss_streak < 8) {
            #pragma unroll 1
            for (int r = 0; r < 4 && !mine; r++) {
                __builtin_amdgcn_s_sleep(1);
                xq_raw = ld_raw(rp(t));
                mine = ((unsigned)(xq_raw >> 32) == stamp);
            }
        }
        const int wok = __all(mine) ? 1 : 0;
        if ((tid & 63) == 0) okf[d_g] = wok;
        __syncthreads();   // B1: Mh + okf ready
        const bool allok = okf[0] && okf[1] && okf[2] && okf[3];

        float xq;
        if (allok) {
            xq = __uint_as_float((unsigned)xq_raw);
            miss_streak = 0;
        } else {
            // local fallback: exact legacy XFIN arithmetic (weights from L2)
            miss_streak++;
            const float4 xv = *(const float4*)(edges + (size_t)erow(i) * kF + 4 * jl2);
            *(float4*)(&x_s[d_g][4 * jl2]) = xv;
            __syncthreads();
            const float* wr = WihC + (size_t)Jg2 * kF + d_g * 64;
            float p0 = 0.f, p1 = 0.f, p2 = 0.f, p3 = 0.f;
            #pragma unroll
            for (int k4 = 0; k4 < 16; k4++) {
                float4 wv = *(const float4*)(wr + k4 * 4);
                float4 a0 = *(const float4*)&x_s[0][d_g * 64 + k4 * 4];
                float4 a1 = *(const float4*)&x_s[1][d_g * 64 + k4 * 4];
                float4 a2 = *(const float4*)&x_s[2][d_g * 64 + k4 * 4];
                float4 a3 = *(const float4*)&x_s[3][d_g * 64 + k4 * 4];
                p0 += wv.x*a0.x + wv.y*a0.y + wv.z*a0.z + wv.w*a0.w;
                p1 += wv.x*a1.x + wv.y*a1.y + wv.z*a1.z + wv.w*a1.w;
                p2 += wv.x*a2.x + wv.y*a2.y + wv.z*a2.z + wv.w*a2.w;
                p3 += wv.x*a3.x + wv.y*a3.y + wv.z*a3.z + wv.w*a3.w;
            }
            xpart[d_g][0][jl2] = p0; xpart[d_g][1][jl2] = p1;
            xpart[d_g][2][jl2] = p2; xpart[d_g][3][jl2] = p3;
            __syncthreads();
            xq = biaC[Jg2] + xpart[0][d_g][jl2] + xpart[1][d_g][jl2]
                           + xpart[2][d_g][jl2] + xpart[3][d_g][jl2];
        }
        // slot t consumed by all threads -> let the producer advance
        if (tid == 0)
            __hip_atomic_store(&prog[dir * 32 + b], t + 1, __ATOMIC_RELAXED,
                               __HIP_MEMORY_SCOPE_AGENT);

        const float zxv = baR + wax0 * exv.x + wax1 * exv.y + wax2 * exv.z;

        // ---- B: fused per-wave cell (wave = arc, lanes<16) + publish h ----
        const int pp = dir ? i + 1 + d_g : i - 1 - d_g;
        const bool v3 = dir ? (pp < kN) : (pp >= 0);
        const float xi = __shfl(xq, s3m);
        const float xf = __shfl(xq, 16 + s3m);
        const float xg = __shfl(xq, 32 + s3m);
        const float xo = __shfl(xq, 48 + s3m);
        if (jl2 < 16) {
            const int s3 = jl2;
            float gi = xi + Mh[pp & 3][s3];
            float gf = xf + Mh[pp & 3][16 + s3];
            float gg = xg + Mh[pp & 3][32 + s3];
            float go = xo + Mh[pp & 3][48 + s3];
            float cp = cring[pp & 3][s3];
            float c = sigm(gf) * cp + sigm(gi) * tanhf(gg);
            float h = sigm(go) * tanhf(c);
            float hm = v3 ? h : 0.f, cm = v3 ? c : 0.f;
            harcl[d_g][s3] = hm; carcl[d_g][s3] = cm;
            st_pair(hpay + (((dir * 2 + par) * 4 + d_g) << 9) + b * 16 + s3, hm, stamp);
            arc[((size_t)i * 4 + d_g) * kH + b * 16 + s3] = __float2bfloat16(hm);
        }
        // z partial over own 16 h-dims (intra-wave harcl dep -> no barrier)
        {
            float zp = 0.f;
            #pragma unroll
            for (int ss = 0; ss < 16; ss++) zp += WaS[a_id][ss] * harcl[d_g][ss];
            st_pair(zpay + (((dir * 2 + par) * 32 + b) << 8) + tid, zp, stamp);
        }

        // ---- E: batched stamped loads, z-spin then h-spin (legacy shape) ----
        const ull* zb = zpay + (((size_t)(dir * 2 + par) * 32) << 8) + tid;
        ull zv_[32];
        #pragma unroll
        for (int bb = 0; bb < 32; bb++) zv_[bb] = ld_raw(zb + ((size_t)bb << 8));
        const ull* hb = hpay + (((size_t)(dir * 2 + par) * 4) << 9);
        ull hv_[8];
        #pragma unroll
        for (int dd = 0; dd < 4; dd++) {
            hv_[2*dd]   = ld_raw(hb + (dd << 9) + 2 * tid);
            hv_[2*dd+1] = ld_raw(hb + (dd << 9) + 2 * tid + 1);
        }

        for (;;) {
            bool ok = true;
            #pragma unroll
            for (int bb = 0; bb < 32; bb++)
                ok &= ((unsigned)(zv_[bb] >> 32) == stamp);
            if (ok) break;
            __builtin_amdgcn_s_sleep(2);
            #pragma unroll
            for (int bb = 0; bb < 32; bb++)
                if ((unsigned)(zv_[bb] >> 32) != stamp)
                    zv_[bb] = ld_raw(zb + ((size_t)bb << 8));
        }
        float zsum = 0.f;
        #pragma unroll
        for (int bb = 0; bb < 32; bb++) zsum += __uint_as_float((unsigned)zv_[bb]);

        for (;;) {
            bool ok = true;
            #pragma unroll
            for (int q = 0; q < 8; q++)
                ok &= ((unsigned)(hv_[q] >> 32) == stamp);
            if (ok) break;
            __builtin_amdgcn_s_sleep(2);
            #pragma unroll
            for (int dd = 0; dd < 4; dd++) {
                if ((unsigned)(hv_[2*dd]   >> 32) != stamp) hv_[2*dd]   = ld_raw(hb + (dd << 9) + 2 * tid);
                if ((unsigned)(hv_[2*dd+1] >> 32) != stamp) hv_[2*dd+1] = ld_raw(hb + (dd << 9) + 2 * tid + 1);
            }
        }

        float zv = fmaxf(zsum + zxv, 0.f);
        float lv = WaoR * zv;
        #pragma unroll
        for (int o2 = 1; o2 < 64; o2 <<= 1) lv += __shfl_xor(lv, o2);
        if (a_id == 0) {
            logit_l[d_g] = v3 ? tanhf(lv + baoR) : -1e9f;
        }
        __syncthreads();   // B4: logits ready

        float l0 = logit_l[0], l1 = logit_l[1], l2 = logit_l[2], l3 = logit_l[3];
        float mx = fmaxf(fmaxf(l0, l1), fmaxf(l2, l3));
        float e0 = __expf(l0 - mx), e1 = __expf(l1 - mx);
        float e2 = __expf(l2 - mx), e3 = __expf(l3 - mx);
        float inv = 1.f / (e0 + e1 + e2 + e3);
        float wg[4] = { e0 * inv, e1 * inv, e2 * inv, e3 * inv };

        float hn0 = 0.f, hn1 = 0.f;
        #pragma unroll
        for (int dd = 0; dd < 4; dd++) {
            hn0 += wg[dd] * __uint_as_float((unsigned)hv_[2*dd]);
            hn1 += wg[dd] * __uint_as_float((unsigned)hv_[2*dd+1]);
        }
        {
            const int g = 2 * tid;
            const int ch = g >> 7, wi = g & 127;
            hprev_p[ch * 132 + wi]     = hn0;
            hprev_p[ch * 132 + wi + 1] = hn1;
        }
        if (tid < 16) {
            float cn = wg[0] * carcl[0][tid] + wg[1] * carcl[1][tid]
                     + wg[2] * carcl[2][tid] + wg[3] * carcl[3][tid];
            cring[i & 3][tid] = cn;
        }
        __syncthreads();   // B5: hprev/cring ready for next step

        xq_raw = xq_nraw;
        exv = exv_n;
    }
}

// ---------------------------------------------------------------------------
// Legacy recurrent kernel (in-loop xproj) — fallback when ws can't hold even a
// minimal ring. Verbatim round-11 structure (45.6 ms).
// ---------------------------------------------------------------------------
__global__ __launch_bounds__(256, 1) void k_recur_legacy(
    const float* __restrict__ edges,
    const float* __restrict__ Wih_f, const float* __restrict__ Whh_f, const float* __restrict__ b_f,
    const float* __restrict__ Wih_b, const float* __restrict__ Whh_b, const float* __restrict__ b_b,
    const float* __restrict__ Wa, const float* __restrict__ ba,
    const float* __restrict__ Wao, const float* __restrict__ bao,
    __hip_bfloat16* __restrict__ arc_f, __hip_bfloat16* __restrict__ arc_b,
    ull* __restrict__ hpay, ull* __restrict__ zpay, int* __restrict__ claims) {

    __shared__ int s_slot;
    if (threadIdx.x == 0) {
        unsigned xcc = (unsigned)__builtin_amdgcn_s_getreg((31 << 11) | (0 << 6) | 20) & 15u;
        int slot = -1;
        if (xcc <= 1) {
            int c = atomicAdd(&claims[xcc], 1);
            if (c < 32) slot = (int)xcc * 32 + c;
        } else {
            for (int sl = 0; sl < 64; sl++) __builtin_amdgcn_s_sleep(64);
            for (int dd = 0; dd < 2 && slot < 0; dd++) {
                if (__hip_atomic_load(&claims[dd], __ATOMIC_RELAXED,
                                      __HIP_MEMORY_SCOPE_AGENT) < 32) {
                    int c = atomicAdd(&claims[dd], 1);
                    if (c < 32) slot = dd * 32 + c;
                }
            }
        }
        s_slot = slot;
    }
    __syncthreads();
    const int slot = s_slot;
    if (slot < 0) return;
    const int dir = slot >> 5;
    const int b   = slot & 31;

    const float* __restrict__ Whh = dir ? Whh_b : Whh_f;
    const float* __restrict__ Wih = dir ? Wih_b : Wih_f;
    const float* __restrict__ bia = dir ? b_b  : b_f;
    __hip_bfloat16* __restrict__ arc = dir ? arc_b : arc_f;
    const int tid = threadIdx.x;

    const int jl = tid >> 2, ks = tid & 3;
    const int Jg = (jl >> 4) * kH + b * 16 + (jl & 15);
    const int d_g = tid >> 6, jl2 = tid & 63;
    const int Jg2 = (jl2 >> 4) * kH + b * 16 + (jl2 & 15);
    const int a_id = jl2;

    float w[128];
    {
        const float* wr = Whh + (size_t)Jg * kH + ks * 128;
        #pragma unroll
        for (int kk = 0; kk < 128; kk++) w[kk] = wr[kk];
    }
    float wih[64];
    {
        const float* wr = Wih + (size_t)Jg2 * kF + d_g * 64;
        #pragma unroll
        for (int kk = 0; kk < 64; kk++) wih[kk] = wr[kk];
    }
    const float biasR = bia[Jg2];
    const float baR   = ba[a_id];
    const float WaoR  = Wao[a_id];
    const float baoR  = bao[0];
    const float wax0  = Wa[(size_t)a_id * 515 + 512];
    const float wax1  = Wa[(size_t)a_id * 515 + 513];
    const float wax2  = Wa[(size_t)a_id * 515 + 514];

    __shared__ __align__(16) float hprev_p[4 * 132];
    __shared__ float Mh[4][64];
    __shared__ float cring[4][16];
    __shared__ float harcl[4][16];
    __shared__ float carcl[4][16];
    __shared__ float logit_l[4];
    __shared__ float WaS[64][17];
    __shared__ float xpl[2][4][64];
    __shared__ __align__(16) float x_s[4][256];
    __shared__ float xpart[4][4][64];

    for (int l2 = tid; l2 < 4 * 132; l2 += 256) hprev_p[l2] = 0.f;
    Mh[tid >> 6][tid & 63] = 0.f;
    if (tid < 64) cring[tid >> 4][tid & 15] = 0.f;
    for (int l2 = tid; l2 < 1024; l2 += 256)
        WaS[l2 >> 4][l2 & 15] = Wa[(size_t)(l2 >> 4) * 515 + b * 16 + (l2 & 15)];
    __syncthreads();

#define XLOAD(nn, XV) do {                                                    \
        int row_;                                                             \
        if (dir == 0) row_ = (nn) * 4 + d_g;                                  \
        else { row_ = ((nn) + 1 + d_g) * 4 + d_g;                             \
               if (row_ > kE - 1) row_ = kE - 1; }                            \
        XV = *(const float4*)(edges + (size_t)row_ * kF + 4 * jl2);           \
    } while (0)

#define XFIN(XV, BUF, ZXOUT) do {                                             \
        *(float4*)(&x_s[d_g][4 * jl2]) = XV;                                  \
        __syncthreads();                                                      \
        float p0_ = 0.f, p1_ = 0.f, p2_ = 0.f, p3_ = 0.f;                     \
        _Pragma("unroll")                                                     \
        for (int k4_ = 0; k4_ < 16; k4_++) {                                  \
            float4 a0_ = *(const float4*)&x_s[0][d_g * 64 + k4_ * 4];         \
            float4 a1_ = *(const float4*)&x_s[1][d_g * 64 + k4_ * 4];         \
            float4 a2_ = *(const float4*)&x_s[2][d_g * 64 + k4_ * 4];         \
            float4 a3_ = *(const float4*)&x_s[3][d_g * 64 + k4_ * 4];         \
            float w0_ = wih[k4_*4], w1_ = wih[k4_*4+1];                       \
            float w2_ = wih[k4_*4+2], w3_ = wih[k4_*4+3];                     \
            p0_ += w0_*a0_.x + w1_*a0_.y + w2_*a0_.z + w3_*a0_.w;             \
            p1_ += w0_*a1_.x + w1_*a1_.y + w2_*a1_.z + w3_*a1_.w;             \
            p2_ += w0_*a2_.x + w1_*a2_.y + w2_*a2_.z + w3_*a2_.w;             \
            p3_ += w0_*a3_.x + w1_*a3_.y + w2_*a3_.z + w3_*a3_.w;             \
        }                                                                     \
        xpart[d_g][0][jl2] = p0_; xpart[d_g][1][jl2] = p1_;                   \
        xpart[d_g][2][jl2] = p2_; xpart[d_g][3][jl2] = p3_;                   \
        __syncthreads();                                                      \
        xpl[BUF][d_g][jl2] = biasR + xpart[0][d_g][jl2] + xpart[1][d_g][jl2]  \
                                   + xpart[2][d_g][jl2] + xpart[3][d_g][jl2]; \
        ZXOUT = baR + wax0 * x_s[d_g][0] + wax1 * x_s[d_g][1]                 \
                    + wax2 * x_s[d_g][2];                                     \
    } while (0)

    const int i0 = dir ? kN - 1 : 0;
    float zxv, zx_n;
    {
        float4 xv0;
        XLOAD(i0, xv0);
        XFIN(xv0, 0, zxv);
    }
    __syncthreads();

    for (int t = 0; t < kN; t++) {
        const int i = dir ? kN - 1 - t : t;
        const unsigned stamp = (unsigned)(t + 1);
        const int par = t & 1;

        float4 xv_n;
        {
            const int nn = (t + 1 < kN) ? (dir ? i - 1 : i + 1) : i;
            XLOAD(nn, xv_n);
        }

        float acc = 0.f;
        {
            const float* hp = &hprev_p[ks * 132];
            #pragma unroll
            for (int kk = 0; kk < 128; kk += 4) {
                float4 hv = *(const float4*)(hp + kk);
                acc += w[kk] * hv.x + w[kk+1] * hv.y + w[kk+2] * hv.z + w[kk+3] * hv.w;
            }
        }
        acc += __shfl_xor(acc, 1);
        acc += __shfl_xor(acc, 2);
        const int iprev = dir ? i + 1 : i - 1;
        if (ks == 0) Mh[iprev & 3][jl] = acc;
        __syncthreads();

        const int pp = dir ? i + 1 + d_g : i - 1 - d_g;
        const bool v3 = dir ? (pp < kN) : (pp >= 0);
        if (jl2 < 16) {
            const int s3 = jl2;
            float gi = xpl[par][d_g][s3]      + Mh[pp & 3][s3];
            float gf = xpl[par][d_g][16 + s3] + Mh[pp & 3][16 + s3];
            float gg = xpl[par][d_g][32 + s3] + Mh[pp & 3][32 + s3];
            float go = xpl[par][d_g][48 + s3] + Mh[pp & 3][48 + s3];
            float cp = cring[pp & 3][s3];
            float c = sigm(gf) * cp + sigm(gi) * tanhf(gg);
            float h = sigm(go) * tanhf(c);
            float hm = v3 ? h : 0.f, cm = v3 ? c : 0.f;
            harcl[d_g][s3] = hm; carcl[d_g][s3] = cm;
            st_pair(hpay + (((dir * 2 + par) * 4 + d_g) << 9) + b * 16 + s3, hm, stamp);
            arc[((size_t)i * 4 + d_g) * kH + b * 16 + s3] = __float2bfloat16(hm);
        }
        {
            float zp = 0.f;
            #pragma unroll
            for (int ss = 0; ss < 16; ss++) zp += WaS[a_id][ss] * harcl[d_g][ss];
            st_pair(zpay + (((dir * 2 + par) * 32 + b) << 8) + tid, zp, stamp);
        }

        float xp_dummy; (void)xp_dummy;
        XFIN(xv_n, par ^ 1, zx_n);

        const ull* zb = zpay + (((size_t)(dir * 2 + par) * 32) << 8) + tid;
        ull zv_[32];
        #pragma unroll
        for (int bb = 0; bb < 32; bb++) zv_[bb] = ld_raw(zb + ((size_t)bb << 8));
        const ull* hb = hpay + (((size_t)(dir * 2 + par) * 4) << 9);
        ull hv_[8];
        #pragma unroll
        for (int dd = 0; dd < 4; dd++) {
            hv_[2*dd]   = ld_raw(hb + (dd << 9) + 2 * tid);
            hv_[2*dd+1] = ld_raw(hb + (dd << 9) + 2 * tid + 1);
        }

        for (;;) {
            bool ok = true;
            #pragma unroll
            for (int bb = 0; bb < 32; bb++)
                ok &= ((unsigned)(zv_[bb] >> 32) == stamp);
            if (ok) break;
            __builtin_amdgcn_s_sleep(2);
            #pragma unroll
            for (int bb = 0; bb < 32; bb++)
                if ((unsigned)(zv_[bb] >> 32) != stamp)
                    zv_[bb] = ld_raw(zb + ((size_t)bb << 8));
        }
        float zsum = 0.f;
        #pragma unroll
        for (int bb = 0; bb < 32; bb++) zsum += __uint_as_float((unsigned)zv_[bb]);

        for (;;) {
            bool ok = true;
            #pragma unroll
            for (int q = 0; q < 8; q++)
                ok &= ((unsigned)(hv_[q] >> 32) == stamp);
            if (ok) break;
            __builtin_amdgcn_s_sleep(2);
            #pragma unroll
            for (int dd = 0; dd < 4; dd++) {
                if ((unsigned)(hv_[2*dd]   >> 32) != stamp) hv_[2*dd]   = ld_raw(hb + (dd << 9) + 2 * tid);
                if ((unsigned)(hv_[2*dd+1] >> 32) != stamp) hv_[2*dd+1] = ld_raw(hb + (dd << 9) + 2 * tid + 1);
            }
        }

        float zv = fmaxf(zsum + zxv, 0.f);
        float lv = WaoR * zv;
        #pragma unroll
        for (int o2 = 1; o2 < 64; o2 <<= 1) lv += __shfl_xor(lv, o2);
        if (a_id == 0) {
            logit_l[d_g] = v3 ? tanhf(lv + baoR) : -1e9f;
        }
        __syncthreads();

        float l0 = logit_l[0], l1 = logit_l[1], l2 = logit_l[2], l3 = logit_l[3];
        float mx = fmaxf(fmaxf(l0, l1), fmaxf(l2, l3));
        float e0 = __expf(l0 - mx), e1 = __expf(l1 - mx);
        float e2 = __expf(l2 - mx), e3 = __expf(l3 - mx);
        float inv = 1.f / (e0 + e1 + e2 + e3);
        float wg[4] = { e0 * inv, e1 * inv, e2 * inv, e3 * inv };

        float hn0 = 0.f, hn1 = 0.f;
        #pragma unroll
        for (int dd = 0; dd < 4; dd++) {
            hn0 += wg[dd] * __uint_as_float((unsigned)hv_[2*dd]);
            hn1 += wg[dd] * __uint_as_float((unsigned)hv_[2*dd+1]);
        }
        {
            const int g = 2 * tid;
            const int ch = g >> 7, wi = g & 127;
            hprev_p[ch * 132 + wi]     = hn0;
            hprev_p[ch * 132 + wi + 1] = hn1;
        }
        if (tid < 16) {
            float cn = wg[0] * carcl[0][tid] + wg[1] * carcl[1][tid]
                     + wg[2] * carcl[2][tid] + wg[3] * carcl[3][tid];
            cring[i & 3][tid] = cn;
        }
        __syncthreads();

        zxv = zx_n;
    }
#undef XLOAD
#undef XFIN
}

// ---------------------------------------------------------------------------
// decoder: out[e] += sum_l Wdo[l] * relu(bd[l] + sum_k Wd[l,k] feat[e,k])
// ---------------------------------------------------------------------------
__global__ __launch_bounds__(256) void k_dec(
    const __hip_bfloat16* __restrict__ arc_f, const __hip_bfloat16* __restrict__ arc_b,
    const float* __restrict__ Wd, const float* __restrict__ bd,
    const float* __restrict__ Wdo, float* __restrict__ out) {
    const int e0 = blockIdx.x * 128;
    const int l0 = blockIdx.y * 128;
    __shared__ __align__(16) float As[8][128];
    __shared__ __align__(16) float Bs[8][128];
    const int tid = threadIdx.x;
    const int tx = tid & 15, ty = tid >> 4;
    const int lr = tid & 127, kq = tid >> 7;

    const int e = e0 + lr;
    const int j = e >> 2, d = e & 3;
    const int jb = j - 1 - d;
    const __hip_bfloat16* frow  = arc_f + (size_t)e * kH;
    const __hip_bfloat16* brow2 = (jb >= 0) ? (arc_b + ((size_t)jb * 4 + d) * kH) : nullptr;
    const float* wrow = Wd + (size_t)(l0 + lr) * (2 * kH);

    float acc[8][8] = {};
    for (int k0 = 0; k0 < 2 * kH; k0 += 8) {
        const int kk = k0 + kq * 4;
        float4 av4;
        if (kk < kH) av4 = ld_bf4(frow + kk);
        else if (brow2) av4 = ld_bf4(brow2 + (kk - kH));
        else av4 = make_float4(0.f, 0.f, 0.f, 0.f);
        float4 bv4 = *(const float4*)(wrow + kk);
        __syncthreads();
        As[kq*4+0][lr] = av4.x; As[kq*4+1][lr] = av4.y;
        As[kq*4+2][lr] = av4.z; As[kq*4+3][lr] = av4.w;
        Bs[kq*4+0][lr] = bv4.x; Bs[kq*4+1][lr] = bv4.y;
        Bs[kq*4+2][lr] = bv4.z; Bs[kq*4+3][lr] = bv4.w;
        __syncthreads();
        #pragma unroll
        for (int kt = 0; kt < 8; kt++) {
            __align__(16) float a0[8], b0[8];
            *(float4*)&a0[0] = *(const float4*)&As[kt][ty*8];
            *(float4*)&a0[4] = *(const float4*)&As[kt][ty*8+4];
            *(float4*)&b0[0] = *(const float4*)&Bs[kt][tx*8];
            *(float4*)&b0[4] = *(const float4*)&Bs[kt][tx*8+4];
            #pragma unroll
            for (int mi = 0; mi < 8; mi++)
                #pragma unroll
                for (int ni = 0; ni < 8; ni++)
                    acc[mi][ni] += a0[mi] * b0[ni];
        }
    }
    #pragma unroll
    for (int mi = 0; mi < 8; mi++) {
        float sacc = 0.f;
        #pragma unroll
        for (int ni = 0; ni < 8; ni++) {
            int l = l0 + tx * 8 + ni;
            sacc += Wdo[l] * fmaxf(acc[mi][ni] + bd[l], 0.f);
        }
        sacc += __shfl_xor(sacc, 1);
        sacc += __shfl_xor(sacc, 2);
        sacc += __shfl_xor(sacc, 4);
        sacc += __shfl_xor(sacc, 8);
        if (tx == 0) atomicAdd(out + e0 + ty * 8 + mi, sacc);
    }
}

// ---------------------------------------------------------------------------
extern "C" void kernel_launch(void* const* d_in, const int* in_sizes, int n_in,
                              void* d_out, int out_size, void* d_ws, size_t ws_size,
                              hipStream_t stream) {
    const float* edges = (const float*)d_in[0];
    const float* Wih_f = (const float*)d_in[1];
    const float* Whh_f = (const float*)d_in[2];
    const float* b_f   = (const float*)d_in[3];
    const float* Wih_b = (const float*)d_in[4];
    const float* Whh_b = (const float*)d_in[5];
    const float* b_b   = (const float*)d_in[6];
    const float* Wa    = (const float*)d_in[7];
    const float* ba    = (const float*)d_in[8];
    const float* Wao   = (const float*)d_in[9];
    const float* bao   = (const float*)d_in[10];
    const float* Wd    = (const float*)d_in[11];
    const float* bd    = (const float*)d_in[12];
    const float* Wdo   = (const float*)d_in[13];
    const float* bdo   = (const float*)d_in[14];
    float* out = (float*)d_out;

    char* ws = (char*)d_ws;
    size_t off = 0;
    __hip_bfloat16* arc_f = (__hip_bfloat16*)(ws + off); off += (size_t)kE * kH * 2;  // 33.5 MB
    __hip_bfloat16* arc_b = (__hip_bfloat16*)(ws + off); off += (size_t)kE * kH * 2;  // 33.5 MB
    ull* hpay = (ull*)(ws + off); off += (size_t)2 * 2 * 4 * kH * 8;                  // 128 KB
    ull* zpay = (ull*)(ws + off); off += (size_t)2 * 2 * 32 * 256 * 8;                // 256 KB
    int* claims = (int*)(ws + off); off += 256;
    int* prog   = (int*)(ws + off); off += 256;
    const size_t base = off;

    if (ws_size < base) {
        hipLaunchKernelGGL(k_zero, dim3((kE + 255) / 256), dim3(256), 0, stream, out);
        return;
    }

    // ring: R steps x 2 dirs x 32 b-slots x 256 payloads x 8 B = R * 128 KiB
    int R = 0;
    for (int cand = 128; cand >= 16; cand >>= 1)
        if (base + (size_t)cand * 131072 <= ws_size) { R = cand; break; }

    if (R > 0) {
        ull* ring = (ull*)(ws + base);
        const long ringN = (long)R * 16384;   // total ull entries (2 dirs)
        hipLaunchKernelGGL(k_init, dim3(512), dim3(256), 0, stream,
                           out, bdo, hpay, zpay, claims, prog, ring, ringN);
        hipLaunchKernelGGL(k_recur_pc, dim3(512), dim3(256), 0, stream,
                           edges, Wih_f, b_f, Wih_b, b_b, Whh_f, Whh_b,
                           Wa, ba, Wao, bao, arc_f, arc_b,
                           hpay, zpay, ring, prog, claims, R - 1);
    } else {
        hipLaunchKernelGGL(k_init, dim3(512), dim3(256), 0, stream,
                           out, bdo, hpay, zpay, claims, prog, hpay, 0L);
        hipLaunchKernelGGL(k_recur_legacy, dim3(512), dim3(256), 0, stream,
                           edges, Wih_f, Whh_f, b_f, Wih_b, Whh_b, b_b,
                           Wa, ba, Wao, bao, arc_f, arc_b, hpay, zpay, claims);
    }

    hipLaunchKernelGGL(k_dec, dim3(kE / 128, kL / 128), dim3(256), 0, stream,
                       arc_f, arc_b, Wd, bd, Wdo, out);
}

// Round 5
// 35968.332 us; speedup vs baseline: 4.5898x; 1.4417x over previous
//
#include <hip/hip_runtime.h>
#include <hip/hip_bf16.h>

// Problem constants
constexpr int kN = 8192;
constexpr int kF = 256;
constexpr int kH = 512;
constexpr int kL = 512;
constexpr int kE = kN * 4;           // 32768 edges

using ull = unsigned long long;

__device__ __forceinline__ float sigm(float x) { return 1.f / (1.f + __expf(-x)); }

__device__ __forceinline__ float4 ld_bf4(const __hip_bfloat16* p) {
    uint2 u = *(const uint2*)p;
    float4 r;
    r.x = __uint_as_float(u.x << 16);
    r.y = __uint_as_float(u.x & 0xffff0000u);
    r.z = __uint_as_float(u.y << 16);
    r.w = __uint_as_float(u.y & 0xffff0000u);
    return r;
}

// stamped 8-byte pair: low = float bits, high = stamp (step+1)
// AGENT (LLC) flavor: used for the cross-XCD ring only.
__device__ __forceinline__ void st_pair(ull* p, float v, unsigned stamp) {
    ull u = ((ull)stamp << 32) | (ull)__float_as_uint(v);
    __hip_atomic_store(p, u, __ATOMIC_RELAXED, __HIP_MEMORY_SCOPE_AGENT);
}
__device__ __forceinline__ ull ld_raw(const ull* p) {
    return __hip_atomic_load(p, __ATOMIC_RELAXED, __HIP_MEMORY_SCOPE_AGENT);
}

// XCD-local (L2, sc0) flavor: all communicating blocks of one direction are
// pinned to a single XCD, whose L2 is their common coherence point. sc0 =
// bypass L1, operate at L2 (~200cy) instead of agent/LLC (~1us turnaround).
// Stamps keep this fence-free: a stale read simply fails the stamp and
// retries, so no release/acquire or cache maintenance is needed.
__device__ __forceinline__ void st_sc0(ull* p, float v, unsigned stamp) {
    ull u = ((ull)stamp << 32) | (ull)__float_as_uint(v);
    asm volatile("global_store_dwordx2 %0, %1, off sc0"
                 :: "v"(p), "v"(u) : "memory");
}
// issue 8 independent sc0 loads (no waitcnt here; caller does VWAIT once)
__device__ __forceinline__ void ld8_sc0(ull* r,
        const ull* a0, const ull* a1, const ull* a2, const ull* a3,
        const ull* a4, const ull* a5, const ull* a6, const ull* a7) {
    asm volatile(
        "global_load_dwordx2 %0, %8, off sc0\n\t"
        "global_load_dwordx2 %1, %9, off sc0\n\t"
        "global_load_dwordx2 %2, %10, off sc0\n\t"
        "global_load_dwordx2 %3, %11, off sc0\n\t"
        "global_load_dwordx2 %4, %12, off sc0\n\t"
        "global_load_dwordx2 %5, %13, off sc0\n\t"
        "global_load_dwordx2 %6, %14, off sc0\n\t"
        "global_load_dwordx2 %7, %15, off sc0"
        : "=&v"(r[0]), "=&v"(r[1]), "=&v"(r[2]), "=&v"(r[3]),
          "=&v"(r[4]), "=&v"(r[5]), "=&v"(r[6]), "=&v"(r[7])
        : "v"(a0), "v"(a1), "v"(a2), "v"(a3),
          "v"(a4), "v"(a5), "v"(a6), "v"(a7)
        : "memory");
}
// drain all issued loads, then fence the scheduler so no consumer of the
// asm outputs is hoisted above the waitcnt (rule #18).
#define VWAIT() do { asm volatile("s_waitcnt vmcnt(0)" ::: "memory"); \
                     __builtin_amdgcn_sched_barrier(0); } while (0)

// ---------------------------------------------------------------------------
__global__ void k_init(float* __restrict__ out, const float* __restrict__ bdo,
                       ull* __restrict__ hpay, ull* __restrict__ zpay,
                       int* __restrict__ claims, int* __restrict__ prog,
                       ull* __restrict__ ring, long ringN) {
    int idx = blockIdx.x * 256 + threadIdx.x;
    if (idx < kE) out[idx] = bdo[0];
    if (idx < 2 * 2 * 4 * kH) hpay[idx] = 0ull;
    if (idx < 2 * 2 * 32 * 256) zpay[idx] = 0ull;
    if (idx < 4) claims[idx] = 0;
    if (idx < 64) prog[idx] = 0;
    for (long r = idx; r < ringN; r += (long)gridDim.x * 256) ring[r] = 0ull;
}

__global__ void k_zero(float* __restrict__ out) {
    int idx = blockIdx.x * 256 + threadIdx.x;
    if (idx < kE) out[idx] = 0.f;
}

// ---------------------------------------------------------------------------
// Producer/consumer recurrent kernel, XCD-local-exchange version.
// Roles by XCD at 1 block/CU:
//   xcc0: consumers dir0   xcc1: consumers dir1   (32 each)
//   xcc2: producers dir0   xcc3: producers dir1   (32 each)
// h/z payload exchange among consumers of one dir is WITHIN one XCD ->
// sc0 (L2-point) loads/stores, not agent/LLC. Ring + prog stay agent
// (cross-XCD, prefetched one step ahead so latency is irrelevant).
// Fallback-scan claims PRODUCER slots only: a consumer on a foreign XCD
// would break sc0 coherence; 512 blocks at 1 block/CU guarantee >=32
// native blocks per XCD (held in rounds 3-4).
// ---------------------------------------------------------------------------
__global__ __launch_bounds__(256, 1) void k_recur_pc(
    const float* __restrict__ edges,
    const float* __restrict__ Wih_f, const float* __restrict__ b_f,
    const float* __restrict__ Wih_b, const float* __restrict__ b_b,
    const float* __restrict__ Whh_f, const float* __restrict__ Whh_b,
    const float* __restrict__ Wa, const float* __restrict__ ba,
    const float* __restrict__ Wao, const float* __restrict__ bao,
    __hip_bfloat16* __restrict__ arc_f, __hip_bfloat16* __restrict__ arc_b,
    ull* __restrict__ hpay, ull* __restrict__ zpay,
    ull* __restrict__ ring, int* __restrict__ prog, int* __restrict__ claims,
    int Rm) {

    __shared__ int s_role, s_dir, s_b;
    if (threadIdx.x == 0) {
        unsigned xcc = (unsigned)__builtin_amdgcn_s_getreg((31 << 11) | (0 << 6) | 20) & 15u;
        int role = -1, dir = 0, b = 0;
        if (xcc < 4) {
            int c = atomicAdd(&claims[xcc], 1);
            if (c < 32) { role = (int)(xcc >> 1); dir = (int)(xcc & 1); b = c; }
        }
        if (role < 0) {
            for (int sl = 0; sl < 64; sl++) __builtin_amdgcn_s_sleep(64);
            // only producer pools: consumers must be XCD-native (sc0 coherence)
            for (int p = 2; p < 4 && role < 0; p++) {
                if (__hip_atomic_load(&claims[p], __ATOMIC_RELAXED,
                                      __HIP_MEMORY_SCOPE_AGENT) < 32) {
                    int c = atomicAdd(&claims[p], 1);
                    if (c < 32) { role = 1; dir = p & 1; b = c; }
                }
            }
        }
        s_role = role; s_dir = dir; s_b = b;
    }
    __syncthreads();
    const int role = s_role;
    if (role < 0) return;
    const int dir = s_dir;
    const int b   = s_b;
    const int tid = threadIdx.x;
    const int d_g = tid >> 6, jl2 = tid & 63;

    // ring geometry (runtime R = Rm+1)
    const size_t ringDir = ((size_t)(Rm + 1)) << 13;     // R * 32 * 256
    ull* __restrict__ rb = ring + (size_t)dir * ringDir;

    __shared__ __align__(16) float hprev_p[4 * 132];
    __shared__ float Mh[4][64];
    __shared__ float cring[4][16];
    __shared__ float harcl[4][16];
    __shared__ float carcl[4][16];
    __shared__ float logit_l[4];
    __shared__ float WaS[64][17];
    __shared__ __align__(16) float x_s[4][256];
    __shared__ float xpart[4][4][64];
    __shared__ int okf[4];
    __shared__ int s_pr;

    // ---------------- producer role ----------------
    if (role == 1) {
        const float* __restrict__ Wih = dir ? Wih_b : Wih_f;
        const float* __restrict__ bia = dir ? b_b : b_f;
        const int Jg2 = (jl2 >> 4) * kH + b * 16 + (jl2 & 15);
        float wih[64];
        {
            const float* wr = Wih + (size_t)Jg2 * kF + d_g * 64;
            #pragma unroll
            for (int kk = 0; kk < 64; kk++) wih[kk] = wr[kk];
        }
        const float biasR = bia[Jg2];
        const int ahead = Rm - 2;        // may produce step s while s <= prog+ahead

        int s = 0;
        while (s < kN) {
            if (tid == 0) {
                int pr = __hip_atomic_load(&prog[dir * 32 + b], __ATOMIC_RELAXED,
                                           __HIP_MEMORY_SCOPE_AGENT);
                while (pr + ahead < s) {
                    __builtin_amdgcn_s_sleep(16);
                    pr = __hip_atomic_load(&prog[dir * 32 + b], __ATOMIC_RELAXED,
                                           __HIP_MEMORY_SCOPE_AGENT);
                }
                s_pr = pr;
            }
            __syncthreads();             // pacing + orders x_s/xpart reuse
            {
                int pr = s_pr;
                if (pr > s) s = pr;      // fast-forward past consumed steps
            }
            if (s >= kN) break;

            const int i = dir ? kN - 1 - s : s;
            int row;
            if (dir == 0) row = i * 4 + d_g;
            else { row = (i + 1 + d_g) * 4 + d_g; if (row > kE - 1) row = kE - 1; }
            float4 xv = *(const float4*)(edges + (size_t)row * kF + 4 * jl2);

            *(float4*)(&x_s[d_g][4 * jl2]) = xv;
            __syncthreads();
            float p0 = 0.f, p1 = 0.f, p2 = 0.f, p3 = 0.f;
            #pragma unroll
            for (int k4 = 0; k4 < 16; k4++) {
                float4 a0 = *(const float4*)&x_s[0][d_g * 64 + k4 * 4];
                float4 a1 = *(const float4*)&x_s[1][d_g * 64 + k4 * 4];
                float4 a2 = *(const float4*)&x_s[2][d_g * 64 + k4 * 4];
                float4 a3 = *(const float4*)&x_s[3][d_g * 64 + k4 * 4];
                float w0 = wih[k4*4], w1 = wih[k4*4+1];
                float w2 = wih[k4*4+2], w3 = wih[k4*4+3];
                p0 += w0*a0.x + w1*a0.y + w2*a0.z + w3*a0.w;
                p1 += w0*a1.x + w1*a1.y + w2*a1.z + w3*a1.w;
                p2 += w0*a2.x + w1*a2.y + w2*a2.z + w3*a2.w;
                p3 += w0*a3.x + w1*a3.y + w2*a3.z + w3*a3.w;
            }
            xpart[d_g][0][jl2] = p0; xpart[d_g][1][jl2] = p1;
            xpart[d_g][2][jl2] = p2; xpart[d_g][3][jl2] = p3;
            __syncthreads();
            float val = biasR + xpart[0][d_g][jl2] + xpart[1][d_g][jl2]
                              + xpart[2][d_g][jl2] + xpart[3][d_g][jl2];
            st_pair(rb + (((size_t)(s & Rm) * 32 + b) << 8) + tid, val,
                    (unsigned)(s + 1));
            s++;
        }
        return;
    }

    // ---------------- consumer role ----------------
    const float* __restrict__ Whh = dir ? Whh_b : Whh_f;
    const float* __restrict__ WihC = dir ? Wih_b : Wih_f;
    const float* __restrict__ biaC = dir ? b_b : b_f;
    __hip_bfloat16* __restrict__ arc = dir ? arc_b : arc_f;

    const int jl = tid >> 2, ks = tid & 3;
    const int Jg = (jl >> 4) * kH + b * 16 + (jl & 15);
    const int a_id = jl2;
    const int s3m = jl2 & 15;
    const int Jg2 = (jl2 >> 4) * kH + b * 16 + (jl2 & 15);

    float w[128];
    {
        const float* wr = Whh + (size_t)Jg * kH + ks * 128;
        #pragma unroll
        for (int kk = 0; kk < 128; kk++) w[kk] = wr[kk];
    }
    const float WaoR = Wao[a_id];
    const float baoR = bao[0];
    const float baR  = ba[a_id];
    const float wax0 = Wa[(size_t)a_id * 515 + 512];
    const float wax1 = Wa[(size_t)a_id * 515 + 513];
    const float wax2 = Wa[(size_t)a_id * 515 + 514];

    for (int l2 = tid; l2 < 4 * 132; l2 += 256) hprev_p[l2] = 0.f;
    Mh[tid >> 6][tid & 63] = 0.f;
    if (tid < 64) cring[tid >> 4][tid & 15] = 0.f;
    for (int l2 = tid; l2 < 1024; l2 += 256)
        WaS[l2 >> 4][l2 & 15] = Wa[(size_t)(l2 >> 4) * 515 + b * 16 + (l2 & 15)];
    __syncthreads();

    auto rp = [&](int t) -> ull* {
        return rb + (((size_t)(t & Rm) * 32 + b) << 8) + tid;
    };
    auto erow = [&](int i) -> int {
        int r;
        if (dir == 0) r = i * 4 + d_g;
        else { r = (i + 1 + d_g) * 4 + d_g; if (r > kE - 1) r = kE - 1; }
        return r;
    };

    const int i0 = dir ? kN - 1 : 0;
    ull xq_raw = ld_raw(rp(0));
    float4 exv = *(const float4*)(edges + (size_t)erow(i0) * kF);
    int miss_streak = 0;

    for (int t = 0; t < kN; t++) {
        const int i = dir ? kN - 1 - t : t;
        const unsigned stamp = (unsigned)(t + 1);
        const int par = t & 1;

        // ---- A: M[iprev] = hprev . Whh^T (own 64 rows) ----
        float acc = 0.f;
        {
            const float* hp = &hprev_p[ks * 132];
            #pragma unroll
            for (int kk = 0; kk < 128; kk += 4) {
                float4 hv = *(const float4*)(hp + kk);
                acc += w[kk] * hv.x + w[kk+1] * hv.y + w[kk+2] * hv.z + w[kk+3] * hv.w;
            }
        }
        acc += __shfl_xor(acc, 1);
        acc += __shfl_xor(acc, 2);
        const int iprev = dir ? i + 1 : i - 1;
        if (ks == 0) Mh[iprev & 3][jl] = acc;

        // ---- ring-entry vote (bounded retry; block-uniform via okf+B1) ----
        bool mine = ((unsigned)(xq_raw >> 32) == stamp);
        if (!mine && miss_streak < 8) {
            #pragma unroll 1
            for (int r = 0; r < 4 && !mine; r++) {
                __builtin_amdgcn_s_sleep(1);
                xq_raw = ld_raw(rp(t));
                mine = ((unsigned)(xq_raw >> 32) == stamp);
            }
        }
        const int wok = __all(mine) ? 1 : 0;
        if ((tid & 63) == 0) okf[d_g] = wok;
        __syncthreads();   // B1: Mh + okf ready
        const bool allok = okf[0] && okf[1] && okf[2] && okf[3];

        float xq;
        if (allok) {
            xq = __uint_as_float((unsigned)xq_raw);
            miss_streak = 0;
        } else {
            // local fallback: exact legacy XFIN arithmetic (weights from L2)
            miss_streak++;
            const float4 xv = *(const float4*)(edges + (size_t)erow(i) * kF + 4 * jl2);
            *(float4*)(&x_s[d_g][4 * jl2]) = xv;
            __syncthreads();
            const float* wr = WihC + (size_t)Jg2 * kF + d_g * 64;
            float p0 = 0.f, p1 = 0.f, p2 = 0.f, p3 = 0.f;
            #pragma unroll
            for (int k4 = 0; k4 < 16; k4++) {
                float4 wv = *(const float4*)(wr + k4 * 4);
                float4 a0 = *(const float4*)&x_s[0][d_g * 64 + k4 * 4];
                float4 a1 = *(const float4*)&x_s[1][d_g * 64 + k4 * 4];
                float4 a2 = *(const float4*)&x_s[2][d_g * 64 + k4 * 4];
                float4 a3 = *(const float4*)&x_s[3][d_g * 64 + k4 * 4];
                p0 += wv.x*a0.x + wv.y*a0.y + wv.z*a0.z + wv.w*a0.w;
                p1 += wv.x*a1.x + wv.y*a1.y + wv.z*a1.z + wv.w*a1.w;
                p2 += wv.x*a2.x + wv.y*a2.y + wv.z*a2.z + wv.w*a2.w;
                p3 += wv.x*a3.x + wv.y*a3.y + wv.z*a3.z + wv.w*a3.w;
            }
            xpart[d_g][0][jl2] = p0; xpart[d_g][1][jl2] = p1;
            xpart[d_g][2][jl2] = p2; xpart[d_g][3][jl2] = p3;
            __syncthreads();
            xq = biaC[Jg2] + xpart[0][d_g][jl2] + xpart[1][d_g][jl2]
                           + xpart[2][d_g][jl2] + xpart[3][d_g][jl2];
        }
        // slot t consumed by all threads -> let the producer advance
        if (tid == 0)
            __hip_atomic_store(&prog[dir * 32 + b], t + 1, __ATOMIC_RELAXED,
                               __HIP_MEMORY_SCOPE_AGENT);

        const float zxv = baR + wax0 * exv.x + wax1 * exv.y + wax2 * exv.z;

        // ---- B: fused per-wave cell (wave = arc, lanes<16) + publish h ----
        const int pp = dir ? i + 1 + d_g : i - 1 - d_g;
        const bool v3 = dir ? (pp < kN) : (pp >= 0);
        const float xi = __shfl(xq, s3m);
        const float xf = __shfl(xq, 16 + s3m);
        const float xg = __shfl(xq, 32 + s3m);
        const float xo = __shfl(xq, 48 + s3m);
        if (jl2 < 16) {
            const int s3 = jl2;
            float gi = xi + Mh[pp & 3][s3];
            float gf = xf + Mh[pp & 3][16 + s3];
            float gg = xg + Mh[pp & 3][32 + s3];
            float go = xo + Mh[pp & 3][48 + s3];
            float cp = cring[pp & 3][s3];
            float c = sigm(gf) * cp + sigm(gi) * tanhf(gg);
            float h = sigm(go) * tanhf(c);
            float hm = v3 ? h : 0.f, cm = v3 ? c : 0.f;
            harcl[d_g][s3] = hm; carcl[d_g][s3] = cm;
            st_sc0(hpay + (((dir * 2 + par) * 4 + d_g) << 9) + b * 16 + s3, hm, stamp);
            arc[((size_t)i * 4 + d_g) * kH + b * 16 + s3] = __float2bfloat16(hm);
        }
        // z partial over own 16 h-dims (intra-wave harcl dep -> no barrier)
        {
            float zp = 0.f;
            #pragma unroll
            for (int ss = 0; ss < 16; ss++) zp += WaS[a_id][ss] * harcl[d_g][ss];
            st_sc0(zpay + (((dir * 2 + par) * 32 + b) << 8) + tid, zp, stamp);
        }

        // ---- filler: next step's ring + edge prefetch (hides publish lat) ----
        ull xq_nraw;
        float4 exv_n;
        {
            const int tn = (t + 1 < kN) ? t + 1 : t;
            xq_nraw = ld_raw(rp(tn));
            const int nn = dir ? kN - 1 - tn : tn;
            exv_n = *(const float4*)(edges + (size_t)erow(nn) * kF);
        }

        // ---- E: XCD-local (sc0) batched spin, single merged z+h check ----
        const ull* zb = zpay + (((size_t)(dir * 2 + par) * 32) << 8) + tid;
        const ull* hb = hpay + (((size_t)(dir * 2 + par) * 4) << 9) + 2 * tid;
        ull zv_[32], hv_[8];
        for (;;) {
            ld8_sc0(zv_ +  0, zb + (0 << 8), zb + (1 << 8), zb + (2 << 8), zb + (3 << 8),
                              zb + (4 << 8), zb + (5 << 8), zb + (6 << 8), zb + (7 << 8));
            ld8_sc0(zv_ +  8, zb + (8 << 8), zb + (9 << 8), zb + (10 << 8), zb + (11 << 8),
                              zb + (12 << 8), zb + (13 << 8), zb + (14 << 8), zb + (15 << 8));
            ld8_sc0(zv_ + 16, zb + (16 << 8), zb + (17 << 8), zb + (18 << 8), zb + (19 << 8),
                              zb + (20 << 8), zb + (21 << 8), zb + (22 << 8), zb + (23 << 8));
            ld8_sc0(zv_ + 24, zb + (24 << 8), zb + (25 << 8), zb + (26 << 8), zb + (27 << 8),
                              zb + (28 << 8), zb + (29 << 8), zb + (30 << 8), zb + (31 << 8));
            ld8_sc0(hv_, hb, hb + 1, hb + (1 << 9), hb + (1 << 9) + 1,
                         hb + (2 << 9), hb + (2 << 9) + 1, hb + (3 << 9), hb + (3 << 9) + 1);
            VWAIT();
            bool ok = true;
            #pragma unroll
            for (int bb = 0; bb < 32; bb++)
                ok &= ((unsigned)(zv_[bb] >> 32) == stamp);
            #pragma unroll
            for (int q = 0; q < 8; q++)
                ok &= ((unsigned)(hv_[q] >> 32) == stamp);
            if (ok) break;
            __builtin_amdgcn_s_sleep(2);
        }
        float zsum = 0.f;
        #pragma unroll
        for (int bb = 0; bb < 32; bb++) zsum += __uint_as_float((unsigned)zv_[bb]);

        float zv = fmaxf(zsum + zxv, 0.f);
        float lv = WaoR * zv;
        #pragma unroll
        for (int o2 = 1; o2 < 64; o2 <<= 1) lv += __shfl_xor(lv, o2);
        if (a_id == 0) {
            logit_l[d_g] = v3 ? tanhf(lv + baoR) : -1e9f;
        }
        __syncthreads();   // B4: logits ready

        float l0 = logit_l[0], l1 = logit_l[1], l2 = logit_l[2], l3 = logit_l[3];
        float mx = fmaxf(fmaxf(l0, l1), fmaxf(l2, l3));
        float e0 = __expf(l0 - mx), e1 = __expf(l1 - mx);
        float e2 = __expf(l2 - mx), e3 = __expf(l3 - mx);
        float inv = 1.f / (e0 + e1 + e2 + e3);
        float wg[4] = { e0 * inv, e1 * inv, e2 * inv, e3 * inv };

        float hn0 = 0.f, hn1 = 0.f;
        #pragma unroll
        for (int dd = 0; dd < 4; dd++) {
            hn0 += wg[dd] * __uint_as_float((unsigned)hv_[2*dd]);
            hn1 += wg[dd] * __uint_as_float((unsigned)hv_[2*dd+1]);
        }
        {
            const int g = 2 * tid;
            const int ch = g >> 7, wi = g & 127;
            hprev_p[ch * 132 + wi]     = hn0;
            hprev_p[ch * 132 + wi + 1] = hn1;
        }
        if (tid < 16) {
            float cn = wg[0] * carcl[0][tid] + wg[1] * carcl[1][tid]
                     + wg[2] * carcl[2][tid] + wg[3] * carcl[3][tid];
            cring[i & 3][tid] = cn;
        }
        __syncthreads();   // B5: hprev/cring ready for next step

        xq_raw = xq_nraw;
        exv = exv_n;
    }
}

// ---------------------------------------------------------------------------
// Legacy recurrent kernel (in-loop xproj) — fallback when ws can't hold even a
// minimal ring. Verbatim round-11 structure (45.6 ms).
// ---------------------------------------------------------------------------
__global__ __launch_bounds__(256, 1) void k_recur_legacy(
    const float* __restrict__ edges,
    const float* __restrict__ Wih_f, const float* __restrict__ Whh_f, const float* __restrict__ b_f,
    const float* __restrict__ Wih_b, const float* __restrict__ Whh_b, const float* __restrict__ b_b,
    const float* __restrict__ Wa, const float* __restrict__ ba,
    const float* __restrict__ Wao, const float* __restrict__ bao,
    __hip_bfloat16* __restrict__ arc_f, __hip_bfloat16* __restrict__ arc_b,
    ull* __restrict__ hpay, ull* __restrict__ zpay, int* __restrict__ claims) {

    __shared__ int s_slot;
    if (threadIdx.x == 0) {
        unsigned xcc = (unsigned)__builtin_amdgcn_s_getreg((31 << 11) | (0 << 6) | 20) & 15u;
        int slot = -1;
        if (xcc <= 1) {
            int c = atomicAdd(&claims[xcc], 1);
            if (c < 32) slot = (int)xcc * 32 + c;
        } else {
            for (int sl = 0; sl < 64; sl++) __builtin_amdgcn_s_sleep(64);
            for (int dd = 0; dd < 2 && slot < 0; dd++) {
                if (__hip_atomic_load(&claims[dd], __ATOMIC_RELAXED,
                                      __HIP_MEMORY_SCOPE_AGENT) < 32) {
                    int c = atomicAdd(&claims[dd], 1);
                    if (c < 32) slot = dd * 32 + c;
                }
            }
        }
        s_slot = slot;
    }
    __syncthreads();
    const int slot = s_slot;
    if (slot < 0) return;
    const int dir = slot >> 5;
    const int b   = slot & 31;

    const float* __restrict__ Whh = dir ? Whh_b : Whh_f;
    const float* __restrict__ Wih = dir ? Wih_b : Wih_f;
    const float* __restrict__ bia = dir ? b_b  : b_f;
    __hip_bfloat16* __restrict__ arc = dir ? arc_b : arc_f;
    const int tid = threadIdx.x;

    const int jl = tid >> 2, ks = tid & 3;
    const int Jg = (jl >> 4) * kH + b * 16 + (jl & 15);
    const int d_g = tid >> 6, jl2 = tid & 63;
    const int Jg2 = (jl2 >> 4) * kH + b * 16 + (jl2 & 15);
    const int a_id = jl2;

    float w[128];
    {
        const float* wr = Whh + (size_t)Jg * kH + ks * 128;
        #pragma unroll
        for (int kk = 0; kk < 128; kk++) w[kk] = wr[kk];
    }
    float wih[64];
    {
        const float* wr = Wih + (size_t)Jg2 * kF + d_g * 64;
        #pragma unroll
        for (int kk = 0; kk < 64; kk++) wih[kk] = wr[kk];
    }
    const float biasR = bia[Jg2];
    const float baR   = ba[a_id];
    const float WaoR  = Wao[a_id];
    const float baoR  = bao[0];
    const float wax0  = Wa[(size_t)a_id * 515 + 512];
    const float wax1  = Wa[(size_t)a_id * 515 + 513];
    const float wax2  = Wa[(size_t)a_id * 515 + 514];

    __shared__ __align__(16) float hprev_p[4 * 132];
    __shared__ float Mh[4][64];
    __shared__ float cring[4][16];
    __shared__ float harcl[4][16];
    __shared__ float carcl[4][16];
    __shared__ float logit_l[4];
    __shared__ float WaS[64][17];
    __shared__ float xpl[2][4][64];
    __shared__ __align__(16) float x_s[4][256];
    __shared__ float xpart[4][4][64];

    for (int l2 = tid; l2 < 4 * 132; l2 += 256) hprev_p[l2] = 0.f;
    Mh[tid >> 6][tid & 63] = 0.f;
    if (tid < 64) cring[tid >> 4][tid & 15] = 0.f;
    for (int l2 = tid; l2 < 1024; l2 += 256)
        WaS[l2 >> 4][l2 & 15] = Wa[(size_t)(l2 >> 4) * 515 + b * 16 + (l2 & 15)];
    __syncthreads();

#define XLOAD(nn, XV) do {                                                    \
        int row_;                                                             \
        if (dir == 0) row_ = (nn) * 4 + d_g;                                  \
        else { row_ = ((nn) + 1 + d_g) * 4 + d_g;                             \
               if (row_ > kE - 1) row_ = kE - 1; }                            \
        XV = *(const float4*)(edges + (size_t)row_ * kF + 4 * jl2);           \
    } while (0)

#define XFIN(XV, BUF, ZXOUT) do {                                             \
        *(float4*)(&x_s[d_g][4 * jl2]) = XV;                                  \
        __syncthreads();                                                      \
        float p0_ = 0.f, p1_ = 0.f, p2_ = 0.f, p3_ = 0.f;                     \
        _Pragma("unroll")                                                     \
        for (int k4_ = 0; k4_ < 16; k4_++) {                                  \
            float4 a0_ = *(const float4*)&x_s[0][d_g * 64 + k4_ * 4];         \
            float4 a1_ = *(const float4*)&x_s[1][d_g * 64 + k4_ * 4];         \
            float4 a2_ = *(const float4*)&x_s[2][d_g * 64 + k4_ * 4];         \
            float4 a3_ = *(const float4*)&x_s[3][d_g * 64 + k4_ * 4];         \
            float w0_ = wih[k4_*4], w1_ = wih[k4_*4+1];                       \
            float w2_ = wih[k4_*4+2], w3_ = wih[k4_*4+3];                     \
            p0_ += w0_*a0_.x + w1_*a0_.y + w2_*a0_.z + w3_*a0_.w;             \
            p1_ += w0_*a1_.x + w1_*a1_.y + w2_*a1_.z + w3_*a1_.w;             \
            p2_ += w0_*a2_.x + w1_*a2_.y + w2_*a2_.z + w3_*a2_.w;             \
            p3_ += w0_*a3_.x + w1_*a3_.y + w2_*a3_.z + w3_*a3_.w;             \
        }                                                                     \
        xpart[d_g][0][jl2] = p0_; xpart[d_g][1][jl2] = p1_;                   \
        xpart[d_g][2][jl2] = p2_; xpart[d_g][3][jl2] = p3_;                   \
        __syncthreads();                                                      \
        xpl[BUF][d_g][jl2] = biasR + xpart[0][d_g][jl2] + xpart[1][d_g][jl2]  \
                                   + xpart[2][d_g][jl2] + xpart[3][d_g][jl2]; \
        ZXOUT = baR + wax0 * x_s[d_g][0] + wax1 * x_s[d_g][1]                 \
                    + wax2 * x_s[d_g][2];                                     \
    } while (0)

    const int i0 = dir ? kN - 1 : 0;
    float zxv, zx_n;
    {
        float4 xv0;
        XLOAD(i0, xv0);
        XFIN(xv0, 0, zxv);
    }
    __syncthreads();

    for (int t = 0; t < kN; t++) {
        const int i = dir ? kN - 1 - t : t;
        const unsigned stamp = (unsigned)(t + 1);
        const int par = t & 1;

        float4 xv_n;
        {
            const int nn = (t + 1 < kN) ? (dir ? i - 1 : i + 1) : i;
            XLOAD(nn, xv_n);
        }

        float acc = 0.f;
        {
            const float* hp = &hprev_p[ks * 132];
            #pragma unroll
            for (int kk = 0; kk < 128; kk += 4) {
                float4 hv = *(const float4*)(hp + kk);
                acc += w[kk] * hv.x + w[kk+1] * hv.y + w[kk+2] * hv.z + w[kk+3] * hv.w;
            }
        }
        acc += __shfl_xor(acc, 1);
        acc += __shfl_xor(acc, 2);
        const int iprev = dir ? i + 1 : i - 1;
        if (ks == 0) Mh[iprev & 3][jl] = acc;
        __syncthreads();

        const int pp = dir ? i + 1 + d_g : i - 1 - d_g;
        const bool v3 = dir ? (pp < kN) : (pp >= 0);
        if (jl2 < 16) {
            const int s3 = jl2;
            float gi = xpl[par][d_g][s3]      + Mh[pp & 3][s3];
            float gf = xpl[par][d_g][16 + s3] + Mh[pp & 3][16 + s3];
            float gg = xpl[par][d_g][32 + s3] + Mh[pp & 3][32 + s3];
            float go = xpl[par][d_g][48 + s3] + Mh[pp & 3][48 + s3];
            float cp = cring[pp & 3][s3];
            float c = sigm(gf) * cp + sigm(gi) * tanhf(gg);
            float h = sigm(go) * tanhf(c);
            float hm = v3 ? h : 0.f, cm = v3 ? c : 0.f;
            harcl[d_g][s3] = hm; carcl[d_g][s3] = cm;
            st_pair(hpay + (((dir * 2 + par) * 4 + d_g) << 9) + b * 16 + s3, hm, stamp);
            arc[((size_t)i * 4 + d_g) * kH + b * 16 + s3] = __float2bfloat16(hm);
        }
        {
            float zp = 0.f;
            #pragma unroll
            for (int ss = 0; ss < 16; ss++) zp += WaS[a_id][ss] * harcl[d_g][ss];
            st_pair(zpay + (((dir * 2 + par) * 32 + b) << 8) + tid, zp, stamp);
        }

        float xp_dummy; (void)xp_dummy;
        XFIN(xv_n, par ^ 1, zx_n);

        const ull* zb = zpay + (((size_t)(dir * 2 + par) * 32) << 8) + tid;
        ull zv_[32];
        #pragma unroll
        for (int bb = 0; bb < 32; bb++) zv_[bb] = ld_raw(zb + ((size_t)bb << 8));
        const ull* hb = hpay + (((size_t)(dir * 2 + par) * 4) << 9);
        ull hv_[8];
        #pragma unroll
        for (int dd = 0; dd < 4; dd++) {
            hv_[2*dd]   = ld_raw(hb + (dd << 9) + 2 * tid);
            hv_[2*dd+1] = ld_raw(hb + (dd << 9) + 2 * tid + 1);
        }

        for (;;) {
            bool ok = true;
            #pragma unroll
            for (int bb = 0; bb < 32; bb++)
                ok &= ((unsigned)(zv_[bb] >> 32) == stamp);
            if (ok) break;
            __builtin_amdgcn_s_sleep(2);
            #pragma unroll
            for (int bb = 0; bb < 32; bb++)
                if ((unsigned)(zv_[bb] >> 32) != stamp)
                    zv_[bb] = ld_raw(zb + ((size_t)bb << 8));
        }
        float zsum = 0.f;
        #pragma unroll
        for (int bb = 0; bb < 32; bb++) zsum += __uint_as_float((unsigned)zv_[bb]);

        for (;;) {
            bool ok = true;
            #pragma unroll
            for (int q = 0; q < 8; q++)
                ok &= ((unsigned)(hv_[q] >> 32) == stamp);
            if (ok) break;
            __builtin_amdgcn_s_sleep(2);
            #pragma unroll
            for (int dd = 0; dd < 4; dd++) {
                if ((unsigned)(hv_[2*dd]   >> 32) != stamp) hv_[2*dd]   = ld_raw(hb + (dd << 9) + 2 * tid);
                if ((unsigned)(hv_[2*dd+1] >> 32) != stamp) hv_[2*dd+1] = ld_raw(hb + (dd << 9) + 2 * tid + 1);
            }
        }

        float zv = fmaxf(zsum + zxv, 0.f);
        float lv = WaoR * zv;
        #pragma unroll
        for (int o2 = 1; o2 < 64; o2 <<= 1) lv += __shfl_xor(lv, o2);
        if (a_id == 0) {
            logit_l[d_g] = v3 ? tanhf(lv + baoR) : -1e9f;
        }
        __syncthreads();

        float l0 = logit_l[0], l1 = logit_l[1], l2 = logit_l[2], l3 = logit_l[3];
        float mx = fmaxf(fmaxf(l0, l1), fmaxf(l2, l3));
        float e0 = __expf(l0 - mx), e1 = __expf(l1 - mx);
        float e2 = __expf(l2 - mx), e3 = __expf(l3 - mx);
        float inv = 1.f / (e0 + e1 + e2 + e3);
        float wg[4] = { e0 * inv, e1 * inv, e2 * inv, e3 * inv };

        float hn0 = 0.f, hn1 = 0.f;
        #pragma unroll
        for (int dd = 0; dd < 4; dd++) {
            hn0 += wg[dd] * __uint_as_float((unsigned)hv_[2*dd]);
            hn1 += wg[dd] * __uint_as_float((unsigned)hv_[2*dd+1]);
        }
        {
            const int g = 2 * tid;
            const int ch = g >> 7, wi = g & 127;
            hprev_p[ch * 132 + wi]     = hn0;
            hprev_p[ch * 132 + wi + 1] = hn1;
        }
        if (tid < 16) {
            float cn = wg[0] * carcl[0][tid] + wg[1] * carcl[1][tid]
                     + wg[2] * carcl[2][tid] + wg[3] * carcl[3][tid];
            cring[i & 3][tid] = cn;
        }
        __syncthreads();

        zxv = zx_n;
    }
#undef XLOAD
#undef XFIN
}

// ---------------------------------------------------------------------------
// decoder: out[e] += sum_l Wdo[l] * relu(bd[l] + sum_k Wd[l,k] feat[e,k])
// ---------------------------------------------------------------------------
__global__ __launch_bounds__(256) void k_dec(
    const __hip_bfloat16* __restrict__ arc_f, const __hip_bfloat16* __restrict__ arc_b,
    const float* __restrict__ Wd, const float* __restrict__ bd,
    const float* __restrict__ Wdo, float* __restrict__ out) {
    const int e0 = blockIdx.x * 128;
    const int l0 = blockIdx.y * 128;
    __shared__ __align__(16) float As[8][128];
    __shared__ __align__(16) float Bs[8][128];
    const int tid = threadIdx.x;
    const int tx = tid & 15, ty = tid >> 4;
    const int lr = tid & 127, kq = tid >> 7;

    const int e = e0 + lr;
    const int j = e >> 2, d = e & 3;
    const int jb = j - 1 - d;
    const __hip_bfloat16* frow  = arc_f + (size_t)e * kH;
    const __hip_bfloat16* brow2 = (jb >= 0) ? (arc_b + ((size_t)jb * 4 + d) * kH) : nullptr;
    const float* wrow = Wd + (size_t)(l0 + lr) * (2 * kH);

    float acc[8][8] = {};
    for (int k0 = 0; k0 < 2 * kH; k0 += 8) {
        const int kk = k0 + kq * 4;
        float4 av4;
        if (kk < kH) av4 = ld_bf4(frow + kk);
        else if (brow2) av4 = ld_bf4(brow2 + (kk - kH));
        else av4 = make_float4(0.f, 0.f, 0.f, 0.f);
        float4 bv4 = *(const float4*)(wrow + kk);
        __syncthreads();
        As[kq*4+0][lr] = av4.x; As[kq*4+1][lr] = av4.y;
        As[kq*4+2][lr] = av4.z; As[kq*4+3][lr] = av4.w;
        Bs[kq*4+0][lr] = bv4.x; Bs[kq*4+1][lr] = bv4.y;
        Bs[kq*4+2][lr] = bv4.z; Bs[kq*4+3][lr] = bv4.w;
        __syncthreads();
        #pragma unroll
        for (int kt = 0; kt < 8; kt++) {
            __align__(16) float a0[8], b0[8];
            *(float4*)&a0[0] = *(const float4*)&As[kt][ty*8];
            *(float4*)&a0[4] = *(const float4*)&As[kt][ty*8+4];
            *(float4*)&b0[0] = *(const float4*)&Bs[kt][tx*8];
            *(float4*)&b0[4] = *(const float4*)&Bs[kt][tx*8+4];
            #pragma unroll
            for (int mi = 0; mi < 8; mi++)
                #pragma unroll
                for (int ni = 0; ni < 8; ni++)
                    acc[mi][ni] += a0[mi] * b0[ni];
        }
    }
    #pragma unroll
    for (int mi = 0; mi < 8; mi++) {
        float sacc = 0.f;
        #pragma unroll
        for (int ni = 0; ni < 8; ni++) {
            int l = l0 + tx * 8 + ni;
            sacc += Wdo[l] * fmaxf(acc[mi][ni] + bd[l], 0.f);
        }
        sacc += __shfl_xor(sacc, 1);
        sacc += __shfl_xor(sacc, 2);
        sacc += __shfl_xor(sacc, 4);
        sacc += __shfl_xor(sacc, 8);
        if (tx == 0) atomicAdd(out + e0 + ty * 8 + mi, sacc);
    }
}

// ---------------------------------------------------------------------------
extern "C" void kernel_launch(void* const* d_in, const int* in_sizes, int n_in,
                              void* d_out, int out_size, void* d_ws, size_t ws_size,
                              hipStream_t stream) {
    const float* edges = (const float*)d_in[0];
    const float* Wih_f = (const float*)d_in[1];
    const float* Whh_f = (const float*)d_in[2];
    const float* b_f   = (const float*)d_in[3];
    const float* Wih_b = (const float*)d_in[4];
    const float* Whh_b = (const float*)d_in[5];
    const float* b_b   = (const float*)d_in[6];
    const float* Wa    = (const float*)d_in[7];
    const float* ba    = (const float*)d_in[8];
    const float* Wao   = (const float*)d_in[9];
    const float* bao   = (const float*)d_in[10];
    const float* Wd    = (const float*)d_in[11];
    const float* bd    = (const float*)d_in[12];
    const float* Wdo   = (const float*)d_in[13];
    const float* bdo   = (const float*)d_in[14];
    float* out = (float*)d_out;

    char* ws = (char*)d_ws;
    size_t off = 0;
    __hip_bfloat16* arc_f = (__hip_bfloat16*)(ws + off); off += (size_t)kE * kH * 2;  // 33.5 MB
    __hip_bfloat16* arc_b = (__hip_bfloat16*)(ws + off); off += (size_t)kE * kH * 2;  // 33.5 MB
    ull* hpay = (ull*)(ws + off); off += (size_t)2 * 2 * 4 * kH * 8;                  // 128 KB
    ull* zpay = (ull*)(ws + off); off += (size_t)2 * 2 * 32 * 256 * 8;                // 256 KB
    int* claims = (int*)(ws + off); off += 256;
    int* prog   = (int*)(ws + off); off += 256;
    const size_t base = off;

    if (ws_size < base) {
        hipLaunchKernelGGL(k_zero, dim3((kE + 255) / 256), dim3(256), 0, stream, out);
        return;
    }

    // ring: R steps x 2 dirs x 32 b-slots x 256 payloads x 8 B = R * 128 KiB
    int R = 0;
    for (int cand = 128; cand >= 16; cand >>= 1)
        if (base + (size_t)cand * 131072 <= ws_size) { R = cand; break; }

    if (R > 0) {
        ull* ring = (ull*)(ws + base);
        const long ringN = (long)R * 16384;   // total ull entries (2 dirs)
        hipLaunchKernelGGL(k_init, dim3(512), dim3(256), 0, stream,
                           out, bdo, hpay, zpay, claims, prog, ring, ringN);
        hipLaunchKernelGGL(k_recur_pc, dim3(512), dim3(256), 0, stream,
                           edges, Wih_f, b_f, Wih_b, b_b, Whh_f, Whh_b,
                           Wa, ba, Wao, bao, arc_f, arc_b,
                           hpay, zpay, ring, prog, claims, R - 1);
    } else {
        hipLaunchKernelGGL(k_init, dim3(512), dim3(256), 0, stream,
                           out, bdo, hpay, zpay, claims, prog, hpay, 0L);
        hipLaunchKernelGGL(k_recur_legacy, dim3(512), dim3(256), 0, stream,
                           edges, Wih_f, Whh_f, b_f, Wih_b, Whh_b, b_b,
                           Wa, ba, Wao, bao, arc_f, arc_b, hpay, zpay, claims);
    }

    hipLaunchKernelGGL(k_dec, dim3(kE / 128, kL / 128), dim3(256), 0, stream,
                       arc_f, arc_b, Wd, bd, Wdo, out);
}

// Round 9
// 35901.932 us; speedup vs baseline: 4.5983x; 1.0018x over previous
//
#include <hip/hip_runtime.h>
#include <hip/hip_bf16.h>

// Problem constants
constexpr int kN = 8192;
constexpr int kF = 256;
constexpr int kH = 512;
constexpr int kL = 512;
constexpr int kE = kN * 4;           // 32768 edges

using ull = unsigned long long;

__device__ __forceinline__ float sigm(float x) { return 1.f / (1.f + __expf(-x)); }

__device__ __forceinline__ float4 ld_bf4(const __hip_bfloat16* p) {
    uint2 u = *(const uint2*)p;
    float4 r;
    r.x = __uint_as_float(u.x << 16);
    r.y = __uint_as_float(u.x & 0xffff0000u);
    r.z = __uint_as_float(u.y << 16);
    r.w = __uint_as_float(u.y & 0xffff0000u);
    return r;
}

// stamped 8-byte pair: low = float bits, high = stamp
// AGENT (LLC) flavor: cross-XCD ring only.
__device__ __forceinline__ void st_pair(ull* p, float v, unsigned stamp) {
    ull u = ((ull)stamp << 32) | (ull)__float_as_uint(v);
    __hip_atomic_store(p, u, __ATOMIC_RELAXED, __HIP_MEMORY_SCOPE_AGENT);
}
__device__ __forceinline__ ull ld_raw(const ull* p) {
    return __hip_atomic_load(p, __ATOMIC_RELAXED, __HIP_MEMORY_SCOPE_AGENT);
}

// XCD-local (L2, sc0) flavor: all communicating blocks of one direction are
// pinned to one XCD; sc0 loads/stores are coherent at that L2 (~200cy).
// Stamps keep this fence-free (stale read -> stamp mismatch -> retry).
__device__ __forceinline__ void st_sc0(ull* p, float v, unsigned stamp) {
    ull u = ((ull)stamp << 32) | (ull)__float_as_uint(v);
    asm volatile("global_store_dwordx2 %0, %1, off sc0"
                 :: "v"(p), "v"(u) : "memory");
}
__device__ __forceinline__ void ld8_sc0(ull* r,
        const ull* a0, const ull* a1, const ull* a2, const ull* a3,
        const ull* a4, const ull* a5, const ull* a6, const ull* a7) {
    asm volatile(
        "global_load_dwordx2 %0, %8, off sc0\n\t"
        "global_load_dwordx2 %1, %9, off sc0\n\t"
        "global_load_dwordx2 %2, %10, off sc0\n\t"
        "global_load_dwordx2 %3, %11, off sc0\n\t"
        "global_load_dwordx2 %4, %12, off sc0\n\t"
        "global_load_dwordx2 %5, %13, off sc0\n\t"
        "global_load_dwordx2 %6, %14, off sc0\n\t"
        "global_load_dwordx2 %7, %15, off sc0"
        : "=&v"(r[0]), "=&v"(r[1]), "=&v"(r[2]), "=&v"(r[3]),
          "=&v"(r[4]), "=&v"(r[5]), "=&v"(r[6]), "=&v"(r[7])
        : "v"(a0), "v"(a1), "v"(a2), "v"(a3),
          "v"(a4), "v"(a5), "v"(a6), "v"(a7)
        : "memory");
}
#define VWAIT() do { asm volatile("s_waitcnt vmcnt(0)" ::: "memory"); \
                     __builtin_amdgcn_sched_barrier(0); } while (0)

// ---------------------------------------------------------------------------
__global__ void k_init(float* __restrict__ out, const float* __restrict__ bdo,
                       ull* __restrict__ hpay, ull* __restrict__ zpay,
                       int* __restrict__ claims, int* __restrict__ prog,
                       ull* __restrict__ ring, long ringN) {
    int idx = blockIdx.x * 256 + threadIdx.x;
    if (idx < kE) out[idx] = bdo[0];
    if (idx < 2 * 2 * 4 * kH) hpay[idx] = 0ull;
    if (idx < 2 * 2 * 32 * 256) zpay[idx] = 0ull;
    if (idx < 4) claims[idx] = 0;
    if (idx < 64) prog[idx] = 0;
    for (long r = idx; r < ringN; r += (long)gridDim.x * 256) ring[r] = 0ull;
}

__global__ void k_zero(float* __restrict__ out) {
    int idx = blockIdx.x * 256 + threadIdx.x;
    if (idx < kE) out[idx] = 0.f;
}

// ---------------------------------------------------------------------------
// Producer/consumer recurrent kernel, XCD-local-exchange version.
// Roles by XCD at 1 block/CU:
//   xcc0: consumers dir0   xcc1: consumers dir1   (32 each)
//   xcc2: producers dir0   xcc3: producers dir1   (32 each)
// h/z payload exchange among consumers of one dir is WITHIN one XCD ->
// sc0 (L2-point) loads/stores, not agent/LLC. Ring + prog stay agent
// (cross-XCD, prefetched one step ahead so latency is irrelevant).
// Fallback-scan claims PRODUCER slots only: a consumer on a foreign XCD
// would break sc0 coherence; 512 blocks at 1 block/CU guarantee >=32
// native blocks per XCD (held in rounds 3-4).
// ---------------------------------------------------------------------------
__global__ __launch_bounds__(256, 1) void k_recur_pc(
    const float* __restrict__ edges,
    const float* __restrict__ Wih_f, const float* __restrict__ b_f,
    const float* __restrict__ Wih_b, const float* __restrict__ b_b,
    const float* __restrict__ Whh_f, const float* __restrict__ Whh_b,
    const float* __restrict__ Wa, const float* __restrict__ ba,
    const float* __restrict__ Wao, const float* __restrict__ bao,
    __hip_bfloat16* __restrict__ arc_f, __hip_bfloat16* __restrict__ arc_b,
    ull* __restrict__ hpay, ull* __restrict__ zpay,
    ull* __restrict__ ring, int* __restrict__ prog, int* __restrict__ claims,
    int Rm) {

    __shared__ int s_role, s_dir, s_b;
    if (threadIdx.x == 0) {
        unsigned xcc = (unsigned)__builtin_amdgcn_s_getreg((31 << 11) | (0 << 6) | 20) & 15u;
        int role = -1, dir = 0, b = 0;
        if (xcc < 4) {
            int c = atomicAdd(&claims[xcc], 1);
            if (c < 32) { role = (int)(xcc >> 1); dir = (int)(xcc & 1); b = c; }
        }
        if (role < 0) {
            for (int sl = 0; sl < 64; sl++) __builtin_amdgcn_s_sleep(64);
            // only producer pools: consumers must be XCD-native (sc0 coherence)
            for (int p = 2; p < 4 && role < 0; p++) {
                if (__hip_atomic_load(&claims[p], __ATOMIC_RELAXED,
                                      __HIP_MEMORY_SCOPE_AGENT) < 32) {
                    int c = atomicAdd(&claims[p], 1);
                    if (c < 32) { role = 1; dir = p & 1; b = c; }
                }
            }
        }
        s_role = role; s_dir = dir; s_b = b;
    }
    __syncthreads();
    const int role = s_role;
    if (role < 0) return;
    const int dir = s_dir;
    const int b   = s_b;
    const int tid = threadIdx.x;
    const int d_g = tid >> 6, jl2 = tid & 63;

    // ring geometry (runtime R = Rm+1)
    const size_t ringDir = ((size_t)(Rm + 1)) << 13;     // R * 32 * 256
    ull* __restrict__ rb = ring + (size_t)dir * ringDir;

    __shared__ __align__(16) float hprev_p[4 * 132];
    __shared__ float Mh[4][64];
    __shared__ float cring[4][16];
    __shared__ float harcl[4][16];
    __shared__ float carcl[4][16];
    __shared__ float logit_l[4];
    __shared__ float WaS[64][17];
    __shared__ __align__(16) float x_s[4][256];
    __shared__ float xpart[4][4][64];
    __shared__ int okf[4];
    __shared__ int s_pr;

    // ---------------- producer role ----------------
    if (role == 1) {
        const float* __restrict__ Wih = dir ? Wih_b : Wih_f;
        const float* __restrict__ bia = dir ? b_b : b_f;
        const int Jg2 = (jl2 >> 4) * kH + b * 16 + (jl2 & 15);
        float wih[64];
        {
            const float* wr = Wih + (size_t)Jg2 * kF + d_g * 64;
            #pragma unroll
            for (int kk = 0; kk < 64; kk++) wih[kk] = wr[kk];
        }
        const float biasR = bia[Jg2];
        const int ahead = Rm - 2;        // may produce step s while s <= prog+ahead

        int s = 0;
        while (s < kN) {
            if (tid == 0) {
                int pr = __hip_atomic_load(&prog[dir * 32 + b], __ATOMIC_RELAXED,
                                           __HIP_MEMORY_SCOPE_AGENT);
                while (pr + ahead < s) {
                    __builtin_amdgcn_s_sleep(16);
                    pr = __hip_atomic_load(&prog[dir * 32 + b], __ATOMIC_RELAXED,
                                           __HIP_MEMORY_SCOPE_AGENT);
                }
                s_pr = pr;
            }
            __syncthreads();             // pacing + orders x_s/xpart reuse
            {
                int pr = s_pr;
                if (pr > s) s = pr;      // fast-forward past consumed steps
            }
            if (s >= kN) break;

            const int i = dir ? kN - 1 - s : s;
            int row;
            if (dir == 0) row = i * 4 + d_g;
            else { row = (i + 1 + d_g) * 4 + d_g; if (row > kE - 1) row = kE - 1; }
            float4 xv = *(const float4*)(edges + (size_t)row * kF + 4 * jl2);

            *(float4*)(&x_s[d_g][4 * jl2]) = xv;
            __syncthreads();
            float p0 = 0.f, p1 = 0.f, p2 = 0.f, p3 = 0.f;
            #pragma unroll
            for (int k4 = 0; k4 < 16; k4++) {
                float4 a0 = *(const float4*)&x_s[0][d_g * 64 + k4 * 4];
                float4 a1 = *(const float4*)&x_s[1][d_g * 64 + k4 * 4];
                float4 a2 = *(const float4*)&x_s[2][d_g * 64 + k4 * 4];
                float4 a3 = *(const float4*)&x_s[3][d_g * 64 + k4 * 4];
                float w0 = wih[k4*4], w1 = wih[k4*4+1];
                float w2 = wih[k4*4+2], w3 = wih[k4*4+3];
                p0 += w0*a0.x + w1*a0.y + w2*a0.z + w3*a0.w;
                p1 += w0*a1.x + w1*a1.y + w2*a1.z + w3*a1.w;
                p2 += w0*a2.x + w1*a2.y + w2*a2.z + w3*a2.w;
                p3 += w0*a3.x + w1*a3.y + w2*a3.z + w3*a3.w;
            }
            xpart[d_g][0][jl2] = p0; xpart[d_g][1][jl2] = p1;
            xpart[d_g][2][jl2] = p2; xpart[d_g][3][jl2] = p3;
            __syncthreads();
            float val = biasR + xpart[0][d_g][jl2] + xpart[1][d_g][jl2]
                              + xpart[2][d_g][jl2] + xpart[3][d_g][jl2];
            st_pair(rb + (((size_t)(s & Rm) * 32 + b) << 8) + tid, val,
                    (unsigned)(s + 1));
            s++;
        }
        return;
    }

    // ---------------- consumer role ----------------
    const float* __restrict__ Whh = dir ? Whh_b : Whh_f;
    const float* __restrict__ WihC = dir ? Wih_b : Wih_f;
    const float* __restrict__ biaC = dir ? b_b : b_f;
    __hip_bfloat16* __restrict__ arc = dir ? arc_b : arc_f;

    const int jl = tid >> 2, ks = tid & 3;
    const int Jg = (jl >> 4) * kH + b * 16 + (jl & 15);
    const int a_id = jl2;
    const int s3m = jl2 & 15;
    const int Jg2 = (jl2 >> 4) * kH + b * 16 + (jl2 & 15);

    float w[128];
    {
        const float* wr = Whh + (size_t)Jg * kH + ks * 128;
        #pragma unroll
        for (int kk = 0; kk < 128; kk++) w[kk] = wr[kk];
    }
    const float WaoR = Wao[a_id];
    const float baoR = bao[0];
    const float baR  = ba[a_id];
    const float wax0 = Wa[(size_t)a_id * 515 + 512];
    const float wax1 = Wa[(size_t)a_id * 515 + 513];
    const float wax2 = Wa[(size_t)a_id * 515 + 514];

    for (int l2 = tid; l2 < 4 * 132; l2 += 256) hprev_p[l2] = 0.f;
    Mh[tid >> 6][tid & 63] = 0.f;
    if (tid < 64) cring[tid >> 4][tid & 15] = 0.f;
    for (int l2 = tid; l2 < 1024; l2 += 256)
        WaS[l2 >> 4][l2 & 15] = Wa[(size_t)(l2 >> 4) * 515 + b * 16 + (l2 & 15)];
    __syncthreads();

    auto rp = [&](int t) -> ull* {
        return rb + (((size_t)(t & Rm) * 32 + b) << 8) + tid;
    };
    auto erow = [&](int i) -> int {
        int r;
        if (dir == 0) r = i * 4 + d_g;
        else { r = (i + 1 + d_g) * 4 + d_g; if (r > kE - 1) r = kE - 1; }
        return r;
    };

    const int i0 = dir ? kN - 1 : 0;
    ull xq_raw = ld_raw(rp(0));
    float4 exv = *(const float4*)(edges + (size_t)erow(i0) * kF);
    int miss_streak = 0;

    for (int t = 0; t < kN; t++) {
        const int i = dir ? kN - 1 - t : t;
        const unsigned stamp = (unsigned)(t + 1);
        const int par = t & 1;

        // ---- A: M[iprev] = hprev . Whh^T (own 64 rows) ----
        float acc = 0.f;
        {
            const float* hp = &hprev_p[ks * 132];
            #pragma unroll
            for (int kk = 0; kk < 128; kk += 4) {
                float4 hv = *(const float4*)(hp + kk);
                acc += w[kk] * hv.x + w[kk+1] * hv.y + w[kk+2] * hv.z + w[kk+3] * hv.w;
            }
        }
        acc += __shfl_xor(acc, 1);
        acc += __shfl_xor(acc, 2);
        const int iprev = dir ? i + 1 : i - 1;
        if (ks == 0) Mh[iprev & 3][jl] = acc;

        // ---- ring-entry vote (bounded retry; block-uniform via okf+B1) ----
        bool mine = ((unsigned)(xq_raw >> 32) == stamp);
        if (!mine && miss_streak < 8) {
            #pragma unroll 1
            for (int r = 0; r < 4 && !mine; r++) {
                __builtin_amdgcn_s_sleep(1);
                xq_raw = ld_raw(rp(t));
                mine = ((unsigned)(xq_raw >> 32) == stamp);
            }
        }
        const int wok = __all(mine) ? 1 : 0;
        if ((tid & 63) == 0) okf[d_g] = wok;
        __syncthreads();   // B1: Mh + okf ready
        const bool allok = okf[0] && okf[1] && okf[2] && okf[3];

        float xq;
        if (allok) {
            xq = __uint_as_float((unsigned)xq_raw);
            miss_streak = 0;
        } else {
            // local fallback: exact legacy XFIN arithmetic (weights from L2)
            miss_streak++;
            const float4 xv = *(const float4*)(edges + (size_t)erow(i) * kF + 4 * jl2);
            *(float4*)(&x_s[d_g][4 * jl2]) = xv;
            __syncthreads();
            const float* wr = WihC + (size_t)Jg2 * kF + d_g * 64;
            float p0 = 0.f, p1 = 0.f, p2 = 0.f, p3 = 0.f;
            #pragma unroll
            for (int k4 = 0; k4 < 16; k4++) {
                float4 wv = *(const float4*)(wr + k4 * 4);
                float4 a0 = *(const float4*)&x_s[0][d_g * 64 + k4 * 4];
                float4 a1 = *(const float4*)&x_s[1][d_g * 64 + k4 * 4];
                float4 a2 = *(const float4*)&x_s[2][d_g * 64 + k4 * 4];
                float4 a3 = *(const float4*)&x_s[3][d_g * 64 + k4 * 4];
                p0 += wv.x*a0.x + wv.y*a0.y + wv.z*a0.z + wv.w*a0.w;
                p1 += wv.x*a1.x + wv.y*a1.y + wv.z*a1.z + wv.w*a1.w;
                p2 += wv.x*a2.x + wv.y*a2.y + wv.z*a2.z + wv.w*a2.w;
                p3 += wv.x*a3.x + wv.y*a3.y + wv.z*a3.z + wv.w*a3.w;
            }
            xpart[d_g][0][jl2] = p0; xpart[d_g][1][jl2] = p1;
            xpart[d_g][2][jl2] = p2; xpart[d_g][3][jl2] = p3;
            __syncthreads();
            xq = biaC[Jg2] + xpart[0][d_g][jl2] + xpart[1][d_g][jl2]
                           + xpart[2][d_g][jl2] + xpart[3][d_g][jl2];
        }
        // slot t consumed by all threads -> let the producer advance
        if (tid == 0)
            __hip_atomic_store(&prog[dir * 32 + b], t + 1, __ATOMIC_RELAXED,
                               __HIP_MEMORY_SCOPE_AGENT);

        const float zxv = baR + wax0 * exv.x + wax1 * exv.y + wax2 * exv.z;

        // ---- B: fused per-wave cell (wave = arc, lanes<16) + publish h ----
        const int pp = dir ? i + 1 + d_g : i - 1 - d_g;
        const bool v3 = dir ? (pp < kN) : (pp >= 0);
        const float xi = __shfl(xq, s3m);
        const float xf = __shfl(xq, 16 + s3m);
        const float xg = __shfl(xq, 32 + s3m);
        const float xo = __shfl(xq, 48 + s3m);
        if (jl2 < 16) {
            const int s3 = jl2;
            float gi = xi + Mh[pp & 3][s3];
            float gf = xf + Mh[pp & 3][16 + s3];
            float gg = xg + Mh[pp & 3][32 + s3];
            float go = xo + Mh[pp & 3][48 + s3];
            float cp = cring[pp & 3][s3];
            float c = sigm(gf) * cp + sigm(gi) * tanhf(gg);
            float h = sigm(go) * tanhf(c);
            float hm = v3 ? h : 0.f, cm = v3 ? c : 0.f;
            harcl[d_g][s3] = hm; carcl[d_g][s3] = cm;
            st_sc0(hpay + (((dir * 2 + par) * 4 + d_g) << 9) + b * 16 + s3, hm, stamp);
            arc[((size_t)i * 4 + d_g) * kH + b * 16 + s3] = __float2bfloat16(hm);
        }
        // z partial over own 16 h-dims (intra-wave harcl dep -> no barrier)
        {
            float zp = 0.f;
            #pragma unroll
            for (int ss = 0; ss < 16; ss++) zp += WaS[a_id][ss] * harcl[d_g][ss];
            st_sc0(zpay + (((dir * 2 + par) * 32 + b) << 8) + tid, zp, stamp);
        }

        // ---- filler: next step's ring + edge prefetch (hides publish lat) ----
        ull xq_nraw;
        float4 exv_n;
        {
            const int tn = (t + 1 < kN) ? t + 1 : t;
            xq_nraw = ld_raw(rp(tn));
            const int nn = dir ? kN - 1 - tn : tn;
            exv_n = *(const float4*)(edges + (size_t)erow(nn) * kF);
        }

        // ---- E: XCD-local (sc0) batched spin, single merged z+h check ----
        const ull* zb = zpay + (((size_t)(dir * 2 + par) * 32) << 8) + tid;
        const ull* hb = hpay + (((size_t)(dir * 2 + par) * 4) << 9) + 2 * tid;
        ull zv_[32], hv_[8];
        for (;;) {
            ld8_sc0(zv_ +  0, zb + (0 << 8), zb + (1 << 8), zb + (2 << 8), zb + (3 << 8),
                              zb + (4 << 8), zb + (5 << 8), zb + (6 << 8), zb + (7 << 8));
            ld8_sc0(zv_ +  8, zb + (8 << 8), zb + (9 << 8), zb + (10 << 8), zb + (11 << 8),
                              zb + (12 << 8), zb + (13 << 8), zb + (14 << 8), zb + (15 << 8));
            ld8_sc0(zv_ + 16, zb + (16 << 8), zb + (17 << 8), zb + (18 << 8), zb + (19 << 8),
                              zb + (20 << 8), zb + (21 << 8), zb + (22 << 8), zb + (23 << 8));
            ld8_sc0(zv_ + 24, zb + (24 << 8), zb + (25 << 8), zb + (26 << 8), zb + (27 << 8),
                              zb + (28 << 8), zb + (29 << 8), zb + (30 << 8), zb + (31 << 8));
            ld8_sc0(hv_, hb, hb + 1, hb + (1 << 9), hb + (1 << 9) + 1,
                         hb + (2 << 9), hb + (2 << 9) + 1, hb + (3 << 9), hb + (3 << 9) + 1);
            VWAIT();
            bool ok = true;
            #pragma unroll
            for (int bb = 0; bb < 32; bb++)
                ok &= ((unsigned)(zv_[bb] >> 32) == stamp);
            #pragma unroll
            for (int q = 0; q < 8; q++)
                ok &= ((unsigned)(hv_[q] >> 32) == stamp);
            if (ok) break;
            __builtin_amdgcn_s_sleep(2);
        }
        float zsum = 0.f;
        #pragma unroll
        for (int bb = 0; bb < 32; bb++) zsum += __uint_as_float((unsigned)zv_[bb]);

        float zv = fmaxf(zsum + zxv, 0.f);
        float lv = WaoR * zv;
        #pragma unroll
        for (int o2 = 1; o2 < 64; o2 <<= 1) lv += __shfl_xor(lv, o2);
        if (a_id == 0) {
            logit_l[d_g] = v3 ? tanhf(lv + baoR) : -1e9f;
        }
        __syncthreads();   // B4: logits ready

        float l0 = logit_l[0], l1 = logit_l[1], l2 = logit_l[2], l3 = logit_l[3];
        float mx = fmaxf(fmaxf(l0, l1), fmaxf(l2, l3));
        float e0 = __expf(l0 - mx), e1 = __expf(l1 - mx);
        float e2 = __expf(l2 - mx), e3 = __expf(l3 - mx);
        float inv = 1.f / (e0 + e1 + e2 + e3);
        float wg[4] = { e0 * inv, e1 * inv, e2 * inv, e3 * inv };

        float hn0 = 0.f, hn1 = 0.f;
        #pragma unroll
        for (int dd = 0; dd < 4; dd++) {
            hn0 += wg[dd] * __uint_as_float((unsigned)hv_[2*dd]);
            hn1 += wg[dd] * __uint_as_float((unsigned)hv_[2*dd+1]);
        }
        {
            const int g = 2 * tid;
            const int ch = g >> 7, wi = g & 127;
            hprev_p[ch * 132 + wi]     = hn0;
            hprev_p[ch * 132 + wi + 1] = hn1;
        }
        if (tid < 16) {
            float cn = wg[0] * carcl[0][tid] + wg[1] * carcl[1][tid]
                     + wg[2] * carcl[2][tid] + wg[3] * carcl[3][tid];
            cring[i & 3][tid] = cn;
        }
        __syncthreads();   // B5: hprev/cring ready for next step

        xq_raw = xq_nraw;
        exv = exv_n;
    }
}

// ---------------------------------------------------------------------------
// Legacy recurrent kernel (in-loop xproj) — fallback when ws can't hold even a
// minimal ring. Verbatim round-11 structure (45.6 ms).
// ---------------------------------------------------------------------------
__global__ __launch_bounds__(256, 1) void k_recur_legacy(
    const float* __restrict__ edges,
    const float* __restrict__ Wih_f, const float* __restrict__ Whh_f, const float* __restrict__ b_f,
    const float* __restrict__ Wih_b, const float* __restrict__ Whh_b, const float* __restrict__ b_b,
    const float* __restrict__ Wa, const float* __restrict__ ba,
    const float* __restrict__ Wao, const float* __restrict__ bao,
    __hip_bfloat16* __restrict__ arc_f, __hip_bfloat16* __restrict__ arc_b,
    ull* __restrict__ hpay, ull* __restrict__ zpay, int* __restrict__ claims) {

    __shared__ int s_slot;
    if (threadIdx.x == 0) {
        unsigned xcc = (unsigned)__builtin_amdgcn_s_getreg((31 << 11) | (0 << 6) | 20) & 15u;
        int slot = -1;
        if (xcc <= 1) {
            int c = atomicAdd(&claims[xcc], 1);
            if (c < 32) slot = (int)xcc * 32 + c;
        } else {
            for (int sl = 0; sl < 64; sl++) __builtin_amdgcn_s_sleep(64);
            for (int dd = 0; dd < 2 && slot < 0; dd++) {
                if (__hip_atomic_load(&claims[dd], __ATOMIC_RELAXED,
                                      __HIP_MEMORY_SCOPE_AGENT) < 32) {
                    int c = atomicAdd(&claims[dd], 1);
                    if (c < 32) slot = dd * 32 + c;
                }
            }
        }
        s_slot = slot;
    }
    __syncthreads();
    const int slot = s_slot;
    if (slot < 0) return;
    const int dir = slot >> 5;
    const int b   = slot & 31;

    const float* __restrict__ Whh = dir ? Whh_b : Whh_f;
    const float* __restrict__ Wih = dir ? Wih_b : Wih_f;
    const float* __restrict__ bia = dir ? b_b  : b_f;
    __hip_bfloat16* __restrict__ arc = dir ? arc_b : arc_f;
    const int tid = threadIdx.x;

    const int jl = tid >> 2, ks = tid & 3;
    const int Jg = (jl >> 4) * kH + b * 16 + (jl & 15);
    const int d_g = tid >> 6, jl2 = tid & 63;
    const int Jg2 = (jl2 >> 4) * kH + b * 16 + (jl2 & 15);
    const int a_id = jl2;

    float w[128];
    {
        const float* wr = Whh + (size_t)Jg * kH + ks * 128;
        #pragma unroll
        for (int kk = 0; kk < 128; kk++) w[kk] = wr[kk];
    }
    float wih[64];
    {
        const float* wr = Wih + (size_t)Jg2 * kF + d_g * 64;
        #pragma unroll
        for (int kk = 0; kk < 64; kk++) wih[kk] = wr[kk];
    }
    const float biasR = bia[Jg2];
    const float baR   = ba[a_id];
    const float WaoR  = Wao[a_id];
    const float baoR  = bao[0];
    const float wax0  = Wa[(size_t)a_id * 515 + 512];
    const float wax1  = Wa[(size_t)a_id * 515 + 513];
    const float wax2  = Wa[(size_t)a_id * 515 + 514];

    __shared__ __align__(16) float hprev_p[4 * 132];
    __shared__ float Mh[4][64];
    __shared__ float cring[4][16];
    __shared__ float harcl[4][16];
    __shared__ float carcl[4][16];
    __shared__ float logit_l[4];
    __shared__ float WaS[64][17];
    __shared__ float xpl[2][4][64];
    __shared__ __align__(16) float x_s[4][256];
    __shared__ float xpart[4][4][64];

    for (int l2 = tid; l2 < 4 * 132; l2 += 256) hprev_p[l2] = 0.f;
    Mh[tid >> 6][tid & 63] = 0.f;
    if (tid < 64) cring[tid >> 4][tid & 15] = 0.f;
    for (int l2 = tid; l2 < 1024; l2 += 256)
        WaS[l2 >> 4][l2 & 15] = Wa[(size_t)(l2 >> 4) * 515 + b * 16 + (l2 & 15)];
    __syncthreads();

#define XLOAD(nn, XV) do {                                                    \
        int row_;                                                             \
        if (dir == 0) row_ = (nn) * 4 + d_g;                                  \
        else { row_ = ((nn) + 1 + d_g) * 4 + d_g;                             \
               if (row_ > kE - 1) row_ = kE - 1; }                            \
        XV = *(const float4*)(edges + (size_t)row_ * kF + 4 * jl2);           \
    } while (0)

#define XFIN(XV, BUF, ZXOUT) do {                                             \
        *(float4*)(&x_s[d_g][4 * jl2]) = XV;                                  \
        __syncthreads();                                                      \
        float p0_ = 0.f, p1_ = 0.f, p2_ = 0.f, p3_ = 0.f;                     \
        _Pragma("unroll")                                                     \
        for (int k4_ = 0; k4_ < 16; k4_++) {                                  \
            float4 a0_ = *(const float4*)&x_s[0][d_g * 64 + k4_ * 4];         \
            float4 a1_ = *(const float4*)&x_s[1][d_g * 64 + k4_ * 4];         \
            float4 a2_ = *(const float4*)&x_s[2][d_g * 64 + k4_ * 4];         \
            float4 a3_ = *(const float4*)&x_s[3][d_g * 64 + k4_ * 4];         \
            float w0_ = wih[k4_*4], w1_ = wih[k4_*4+1];                       \
            float w2_ = wih[k4_*4+2], w3_ = wih[k4_*4+3];                     \
            p0_ += w0_*a0_.x + w1_*a0_.y + w2_*a0_.z + w3_*a0_.w;             \
            p1_ += w0_*a1_.x + w1_*a1_.y + w2_*a1_.z + w3_*a1_.w;             \
            p2_ += w0_*a2_.x + w1_*a2_.y + w2_*a2_.z + w3_*a2_.w;             \
            p3_ += w0_*a3_.x + w1_*a3_.y + w2_*a3_.z + w3_*a3_.w;             \
        }                                                                     \
        xpart[d_g][0][jl2] = p0_; xpart[d_g][1][jl2] = p1_;                   \
        xpart[d_g][2][jl2] = p2_; xpart[d_g][3][jl2] = p3_;                   \
        __syncthreads();                                                      \
        xpl[BUF][d_g][jl2] = biasR + xpart[0][d_g][jl2] + xpart[1][d_g][jl2]  \
                                   + xpart[2][d_g][jl2] + xpart[3][d_g][jl2]; \
        ZXOUT = baR + wax0 * x_s[d_g][0] + wax1 * x_s[d_g][1]                 \
                    + wax2 * x_s[d_g][2];                                     \
    } while (0)

    const int i0 = dir ? kN - 1 : 0;
    float zxv, zx_n;
    {
        float4 xv0;
        XLOAD(i0, xv0);
        XFIN(xv0, 0, zxv);
    }
    __syncthreads();

    for (int t = 0; t < kN; t++) {
        const int i = dir ? kN - 1 - t : t;
        const unsigned stamp = (unsigned)(t + 1);
        const int par = t & 1;

        float4 xv_n;
        {
            const int nn = (t + 1 < kN) ? (dir ? i - 1 : i + 1) : i;
            XLOAD(nn, xv_n);
        }

        float acc = 0.f;
        {
            const float* hp = &hprev_p[ks * 132];
            #pragma unroll
            for (int kk = 0; kk < 128; kk += 4) {
                float4 hv = *(const float4*)(hp + kk);
                acc += w[kk] * hv.x + w[kk+1] * hv.y + w[kk+2] * hv.z + w[kk+3] * hv.w;
            }
        }
        acc += __shfl_xor(acc, 1);
        acc += __shfl_xor(acc, 2);
        const int iprev = dir ? i + 1 : i - 1;
        if (ks == 0) Mh[iprev & 3][jl] = acc;
        __syncthreads();

        const int pp = dir ? i + 1 + d_g : i - 1 - d_g;
        const bool v3 = dir ? (pp < kN) : (pp >= 0);
        if (jl2 < 16) {
            const int s3 = jl2;
            float gi = xpl[par][d_g][s3]      + Mh[pp & 3][s3];
            float gf = xpl[par][d_g][16 + s3] + Mh[pp & 3][16 + s3];
            float gg = xpl[par][d_g][32 + s3] + Mh[pp & 3][32 + s3];
            float go = xpl[par][d_g][48 + s3] + Mh[pp & 3][48 + s3];
            float cp = cring[pp & 3][s3];
            float c = sigm(gf) * cp + sigm(gi) * tanhf(gg);
            float h = sigm(go) * tanhf(c);
            float hm = v3 ? h : 0.f, cm = v3 ? c : 0.f;
            harcl[d_g][s3] = hm; carcl[d_g][s3] = cm;
            st_pair(hpay + (((dir * 2 + par) * 4 + d_g) << 9) + b * 16 + s3, hm, stamp);
            arc[((size_t)i * 4 + d_g) * kH + b * 16 + s3] = __float2bfloat16(hm);
        }
        {
            float zp = 0.f;
            #pragma unroll
            for (int ss = 0; ss < 16; ss++) zp += WaS[a_id][ss] * harcl[d_g][ss];
            st_pair(zpay + (((dir * 2 + par) * 32 + b) << 8) + tid, zp, stamp);
        }

        float xp_dummy; (void)xp_dummy;
        XFIN(xv_n, par ^ 1, zx_n);

        const ull* zb = zpay + (((size_t)(dir * 2 + par) * 32) << 8) + tid;
        ull zv_[32];
        #pragma unroll
        for (int bb = 0; bb < 32; bb++) zv_[bb] = ld_raw(zb + ((size_t)bb << 8));
        const ull* hb = hpay + (((size_t)(dir * 2 + par) * 4) << 9);
        ull hv_[8];
        #pragma unroll
        for (int dd = 0; dd < 4; dd++) {
            hv_[2*dd]   = ld_raw(hb + (dd << 9) + 2 * tid);
            hv_[2*dd+1] = ld_raw(hb + (dd << 9) + 2 * tid + 1);
        }

        for (;;) {
            bool ok = true;
            #pragma unroll
            for (int bb = 0; bb < 32; bb++)
                ok &= ((unsigned)(zv_[bb] >> 32) == stamp);
            if (ok) break;
            __builtin_amdgcn_s_sleep(2);
            #pragma unroll
            for (int bb = 0; bb < 32; bb++)
                if ((unsigned)(zv_[bb] >> 32) != stamp)
                    zv_[bb] = ld_raw(zb + ((size_t)bb << 8));
        }
        float zsum = 0.f;
        #pragma unroll
        for (int bb = 0; bb < 32; bb++) zsum += __uint_as_float((unsigned)zv_[bb]);

        for (;;) {
            bool ok = true;
            #pragma unroll
            for (int q = 0; q < 8; q++)
                ok &= ((unsigned)(hv_[q] >> 32) == stamp);
            if (ok) break;
            __builtin_amdgcn_s_sleep(2);
            #pragma unroll
            for (int dd = 0; dd < 4; dd++) {
                if ((unsigned)(hv_[2*dd]   >> 32) != stamp) hv_[2*dd]   = ld_raw(hb + (dd << 9) + 2 * tid);
                if ((unsigned)(hv_[2*dd+1] >> 32) != stamp) hv_[2*dd+1] = ld_raw(hb + (dd << 9) + 2 * tid + 1);
            }
        }

        float zv = fmaxf(zsum + zxv, 0.f);
        float lv = WaoR * zv;
        #pragma unroll
        for (int o2 = 1; o2 < 64; o2 <<= 1) lv += __shfl_xor(lv, o2);
        if (a_id == 0) {
            logit_l[d_g] = v3 ? tanhf(lv + baoR) : -1e9f;
        }
        __syncthreads();

        float l0 = logit_l[0], l1 = logit_l[1], l2 = logit_l[2], l3 = logit_l[3];
        float mx = fmaxf(fmaxf(l0, l1), fmaxf(l2, l3));
        float e0 = __expf(l0 - mx), e1 = __expf(l1 - mx);
        float e2 = __expf(l2 - mx), e3 = __expf(l3 - mx);
        float inv = 1.f / (e0 + e1 + e2 + e3);
        float wg[4] = { e0 * inv, e1 * inv, e2 * inv, e3 * inv };

        float hn0 = 0.f, hn1 = 0.f;
        #pragma unroll
        for (int dd = 0; dd < 4; dd++) {
            hn0 += wg[dd] * __uint_as_float((unsigned)hv_[2*dd]);
            hn1 += wg[dd] * __uint_as_float((unsigned)hv_[2*dd+1]);
        }
        {
            const int g = 2 * tid;
            const int ch = g >> 7, wi = g & 127;
            hprev_p[ch * 132 + wi]     = hn0;
            hprev_p[ch * 132 + wi + 1] = hn1;
        }
        if (tid < 16) {
            float cn = wg[0] * carcl[0][tid] + wg[1] * carcl[1][tid]
                     + wg[2] * carcl[2][tid] + wg[3] * carcl[3][tid];
            cring[i & 3][tid] = cn;
        }
        __syncthreads();

        zxv = zx_n;
    }
#undef XLOAD
#undef XFIN
}

// ---------------------------------------------------------------------------
// decoder: out[e] += sum_l Wdo[l] * relu(bd[l] + sum_k Wd[l,k] feat[e,k])
// ---------------------------------------------------------------------------
__global__ __launch_bounds__(256) void k_dec(
    const __hip_bfloat16* __restrict__ arc_f, const __hip_bfloat16* __restrict__ arc_b,
    const float* __restrict__ Wd, const float* __restrict__ bd,
    const float* __restrict__ Wdo, float* __restrict__ out) {
    const int e0 = blockIdx.x * 128;
    const int l0 = blockIdx.y * 128;
    __shared__ __align__(16) float As[8][128];
    __shared__ __align__(16) float Bs[8][128];
    const int tid = threadIdx.x;
    const int tx = tid & 15, ty = tid >> 4;
    const int lr = tid & 127, kq = tid >> 7;

    const int e = e0 + lr;
    const int j = e >> 2, d = e & 3;
    const int jb = j - 1 - d;
    const __hip_bfloat16* frow  = arc_f + (size_t)e * kH;
    const __hip_bfloat16* brow2 = (jb >= 0) ? (arc_b + ((size_t)jb * 4 + d) * kH) : nullptr;
    const float* wrow = Wd + (size_t)(l0 + lr) * (2 * kH);

    float acc[8][8] = {};
    for (int k0 = 0; k0 < 2 * kH; k0 += 8) {
        const int kk = k0 + kq * 4;
        float4 av4;
        if (kk < kH) av4 = ld_bf4(frow + kk);
        else if (brow2) av4 = ld_bf4(brow2 + (kk - kH));
        else av4 = make_float4(0.f, 0.f, 0.f, 0.f);
        float4 bv4 = *(const float4*)(wrow + kk);
        __syncthreads();
        As[kq*4+0][lr] = av4.x; As[kq*4+1][lr] = av4.y;
        As[kq*4+2][lr] = av4.z; As[kq*4+3][lr] = av4.w;
        Bs[kq*4+0][lr] = bv4.x; Bs[kq*4+1][lr] = bv4.y;
        Bs[kq*4+2][lr] = bv4.z; Bs[kq*4+3][lr] = bv4.w;
        __syncthreads();
        #pragma unroll
        for (int kt = 0; kt < 8; kt++) {
            __align__(16) float a0[8], b0[8];
            *(float4*)&a0[0] = *(const float4*)&As[kt][ty*8];
            *(float4*)&a0[4] = *(const float4*)&As[kt][ty*8+4];
            *(float4*)&b0[0] = *(const float4*)&Bs[kt][tx*8];
            *(float4*)&b0[4] = *(const float4*)&Bs[kt][tx*8+4];
            #pragma unroll
            for (int mi = 0; mi < 8; mi++)
                #pragma unroll
                for (int ni = 0; ni < 8; ni++)
                    acc[mi][ni] += a0[mi] * b0[ni];
        }
    }
    #pragma unroll
    for (int mi = 0; mi < 8; mi++) {
        float sacc = 0.f;
        #pragma unroll
        for (int ni = 0; ni < 8; ni++) {
            int l = l0 + tx * 8 + ni;
            sacc += Wdo[l] * fmaxf(acc[mi][ni] + bd[l], 0.f);
        }
        sacc += __shfl_xor(sacc, 1);
        sacc += __shfl_xor(sacc, 2);
        sacc += __shfl_xor(sacc, 4);
        sacc += __shfl_xor(sacc, 8);
        if (tx == 0) atomicAdd(out + e0 + ty * 8 + mi, sacc);
    }
}

// ---------------------------------------------------------------------------
extern "C" void kernel_launch(void* const* d_in, const int* in_sizes, int n_in,
                              void* d_out, int out_size, void* d_ws, size_t ws_size,
                              hipStream_t stream) {
    const float* edges = (const float*)d_in[0];
    const float* Wih_f = (const float*)d_in[1];
    const float* Whh_f = (const float*)d_in[2];
    const float* b_f   = (const float*)d_in[3];
    const float* Wih_b = (const float*)d_in[4];
    const float* Whh_b = (const float*)d_in[5];
    const float* b_b   = (const float*)d_in[6];
    const float* Wa    = (const float*)d_in[7];
    const float* ba    = (const float*)d_in[8];
    const float* Wao   = (const float*)d_in[9];
    const float* bao   = (const float*)d_in[10];
    const float* Wd    = (const float*)d_in[11];
    const float* bd    = (const float*)d_in[12];
    const float* Wdo   = (const float*)d_in[13];
    const float* bdo   = (const float*)d_in[14];
    float* out = (float*)d_out;

    char* ws = (char*)d_ws;
    size_t off = 0;
    __hip_bfloat16* arc_f = (__hip_bfloat16*)(ws + off); off += (size_t)kE * kH * 2;  // 33.5 MB
    __hip_bfloat16* arc_b = (__hip_bfloat16*)(ws + off); off += (size_t)kE * kH * 2;  // 33.5 MB
    ull* hpay = (ull*)(ws + off); off += (size_t)2 * 2 * 4 * kH * 8;                  // 128 KB
    ull* zpay = (ull*)(ws + off); off += (size_t)2 * 2 * 32 * 256 * 8;                // 256 KB
    int* claims = (int*)(ws + off); off += 256;
    int* prog   = (int*)(ws + off); off += 256;
    const size_t base = off;

    if (ws_size < base) {
        hipLaunchKernelGGL(k_zero, dim3((kE + 255) / 256), dim3(256), 0, stream, out);
        return;
    }

    // ring: R steps x 2 dirs x 32 b-slots x 256 payloads x 8 B = R * 128 KiB
    int R = 0;
    for (int cand = 128; cand >= 16; cand >>= 1)
        if (base + (size_t)cand * 131072 <= ws_size) { R = cand; break; }

    if (R > 0) {
        ull* ring = (ull*)(ws + base);
        const long ringN = (long)R * 16384;   // total ull entries (2 dirs)
        hipLaunchKernelGGL(k_init, dim3(512), dim3(256), 0, stream,
                           out, bdo, hpay, zpay, claims, prog, ring, ringN);
        hipLaunchKernelGGL(k_recur_pc, dim3(512), dim3(256), 0, stream,
                           edges, Wih_f, b_f, Wih_b, b_b, Whh_f, Whh_b,
                           Wa, ba, Wao, bao, arc_f, arc_b,
                           hpay, zpay, ring, prog, claims, R - 1);
    } else {
        hipLaunchKernelGGL(k_init, dim3(512), dim3(256), 0, stream,
                           out, bdo, hpay, zpay, claims, prog, hpay, 0L);
        hipLaunchKernelGGL(k_recur_legacy, dim3(512), dim3(256), 0, stream,
                           edges, Wih_f, Whh_f, b_f, Wih_b, Whh_b, b_b,
                           Wa, ba, Wao, bao, arc_f, arc_b, hpay, zpay, claims);
    }

    hipLaunchKernelGGL(k_dec, dim3(kE / 128, kL / 128), dim3(256), 0, stream,
                       arc_f, arc_b, Wd, bd, Wdo, out);
}